// Round 18
// baseline (1122.730 us; speedup 1.0000x reference)
//
#include <hip/hip_runtime.h>
#include <cstdint>
#include <cstddef>

#pragma clang fp contract(off)

#define NTOK  32000
#define NINP  512
#define NHID  1024
#define NEXP  10
#define NROW  1024            // N (tokens)
#define NLAT  (NEXP*NINP)     // 5120
#define MROWS (NROW*NEXP)     // 10240

typedef __attribute__((ext_vector_type(4))) float f32x4;
typedef __attribute__((ext_vector_type(8))) short bf16x8;
typedef __attribute__((ext_vector_type(8))) unsigned short us16x8;

// async global->LDS, 16B per lane: LDS dest = wave-uniform base + lane*16
#define GLD16(g, l) __builtin_amdgcn_global_load_lds(                       \
    (const __attribute__((address_space(1))) void*)(g),                     \
    (__attribute__((address_space(3))) void*)(l), 16, 0, 0)

// f32 -> bf16 round-to-nearest-even
__device__ __forceinline__ unsigned short f2b(float x) {
    uint32_t u = __float_as_uint(x);
    uint32_t r = (u + 0x7fffu + ((u >> 16) & 1u)) >> 16;
    return (unsigned short)r;
}
__device__ __forceinline__ float b2f(unsigned short b) {
    return __uint_as_float(((uint32_t)b) << 16);
}

// ---------------------------------------------------------------------------
// threefry2x32 (JAX-exact)
// ---------------------------------------------------------------------------
__device__ __forceinline__ uint32_t rotl32(uint32_t v, int r) {
    return (v << r) | (v >> (32 - r));
}

__device__ __forceinline__ void threefry(uint32_t k0, uint32_t k1,
                                         uint32_t x0, uint32_t x1,
                                         uint32_t& o0, uint32_t& o1) {
    uint32_t k2 = k0 ^ k1 ^ 0x1BD11BDAu;
    x0 += k0; x1 += k1;
#define TF_R(r) { x0 += x1; x1 = rotl32(x1, r); x1 ^= x0; }
    TF_R(13) TF_R(15) TF_R(26) TF_R(6)
    x0 += k1; x1 += k2 + 1u;
    TF_R(17) TF_R(29) TF_R(16) TF_R(24)
    x0 += k2; x1 += k0 + 2u;
    TF_R(13) TF_R(15) TF_R(26) TF_R(6)
    x0 += k0; x1 += k1 + 3u;
    TF_R(17) TF_R(29) TF_R(16) TF_R(24)
    x0 += k1; x1 += k2 + 4u;
    TF_R(13) TF_R(15) TF_R(26) TF_R(6)
    x0 += k2; x1 += k0 + 5u;
#undef TF_R
    o0 = x0; o1 = x1;
}

struct RKey { uint32_t a, b; };

__device__ __forceinline__ RKey kfold(RKey k, uint32_t i) {
    RKey r; threefry(k.a, k.b, 0u, i, r.a, r.b); return r;
}
__device__ __forceinline__ uint32_t kbits(RKey k) {
    uint32_t o0, o1; threefry(k.a, k.b, 0u, 0u, o0, o1); return o0 ^ o1;
}
__device__ __forceinline__ float u01(RKey k) {
    uint32_t b = (kbits(k) >> 9) | 0x3f800000u;
    return __uint_as_float(b) - 1.0f;
}
__device__ __forceinline__ float erfinv_xla(float x) {
    float xx = x * x;
    float w = -log1pf(-xx);
    float p;
    if (w < 5.0f) {
        float ww = w - 2.5f;
        p = 2.81022636e-08f;
        p = p * ww; p = p + 3.43273939e-07f;
        p = p * ww; p = p + -3.5233877e-06f;
        p = p * ww; p = p + -4.39150654e-06f;
        p = p * ww; p = p + 0.00021858087f;
        p = p * ww; p = p + -0.00125372503f;
        p = p * ww; p = p + -0.00417768164f;
        p = p * ww; p = p + 0.246640727f;
        p = p * ww; p = p + 1.50140941f;
    } else {
        float ww = sqrtf(w) - 3.0f;
        p = -0.000200214257f;
        p = p * ww; p = p + 0.000100950558f;
        p = p * ww; p = p + 0.00134934322f;
        p = p * ww; p = p + -0.00367342844f;
        p = p * ww; p = p + 0.00573950773f;
        p = p * ww; p = p + -0.0076224613f;
        p = p * ww; p = p + 0.00943887047f;
        p = p * ww; p = p + 1.00167406f;
        p = p * ww; p = p + 2.83297682f;
    }
    return p * x;
}
__device__ __forceinline__ float norm1(RKey k) {
    const float lo = -0.99999994f;
    float f = u01(k);
    float u = f * 2.0f;
    u = u + lo;
    u = fmaxf(lo, u);
    return 1.41421356f * erfinv_xla(u);
}

__device__ float gamma_log(RKey key, float alpha) {
    const float one_third = 0.33333334f;
    bool boost = (alpha >= 1.0f);
    float alpha_orig = alpha;
    if (!boost) alpha = alpha + 1.0f;
    float d = alpha - one_third;
    float c = one_third / sqrtf(d);

    RKey sub = kfold(key, 1u);
    key      = kfold(key, 0u);
    float log_boost = 0.0f;
    if (!boost) {
        float uB = u01(sub);
        log_boost = log1pf(-uB) * (1.0f / alpha_orig);
    }

    float X = 0.f, V = 1.f, U = 2.f;
    int guard = 0;
    do {
        RKey xk = kfold(key, 1u);
        RKey Uk = kfold(key, 2u);
        key     = kfold(key, 0u);
        float x = 0.f, v = -1.f;
        RKey kin = xk;
        int g2 = 0;
        do {
            RKey sk = kfold(kin, 1u);
            kin     = kfold(kin, 0u);
            x = norm1(sk);
            float cx = x * c;
            v = 1.0f + cx;
        } while (v <= 0.0f && ++g2 < 256);
        X = x * x;
        V = (v * v) * v;
        U = u01(Uk);
        float sq = 1.0f - 0.0331f * (X * X);
        if (U < sq) break;
        float bound = (X * 0.5f) + ((d - d * V) + d * logf(V));
        if (logf(U) < bound) break;
    } while (++guard < 256);

    float ls = logf(d) + logf(V);
    ls = ls + log_boost;
    return ls;
}

// ---------------------------------------------------------------------------
__global__ void k_a(const float* __restrict__ out_in,
                    const float* __restrict__ Wred,
                    const float* __restrict__ bred,
                    float* __restrict__ a_arr, float* __restrict__ dpar) {
    int n = blockIdx.x;
    int lane = threadIdx.x;
    __shared__ float zred[NEXP];
    const float* orow = out_in + (size_t)n * NHID;
    for (int e = 0; e < NEXP; ++e) {
        const float* wrow = Wred + (size_t)e * NHID;
        float s = 0.f;
        for (int k = lane; k < NHID; k += 64) s += orow[k] * wrow[k];
        for (int off = 32; off; off >>= 1) s += __shfl_xor(s, off);
        if (lane == 0) zred[e] = s + bred[e];
    }
    __syncthreads();
    if (lane == 0) {
        float a[NEXP];
        float b = 0.f;
        for (int e = 0; e < NEXP; ++e) {
            float z = zred[e];
            a[e] = fmaxf(z, 0.f) + log1pf(expf(-fabsf(z))) + 1e-8f;
        }
        for (int e = 0; e < NEXP; ++e) b += a[e];
        float cs = 0.f;
        for (int e = 0; e < NEXP; ++e) {
            cs += a[e];
            float dd = fmaxf(fabsf(b - cs), 1e-8f);
            a_arr[n * NEXP + e] = a[e];
            dpar [n * NEXP + e] = dd;
        }
    }
}

__global__ void k_sample(const float* __restrict__ a_arr,
                         const float* __restrict__ dpar,
                         float* __restrict__ sample) {
    int i = blockIdx.x * 256 + threadIdx.x;
    if (i >= MROWS) return;
    RKey root{0u, 42u};
    RKey ka = kfold(root, 0u);
    RKey kb = kfold(root, 1u);
    float lga = gamma_log(kfold(ka, (uint32_t)i), a_arr[i]);
    float lgb = gamma_log(kfold(kb, (uint32_t)i), dpar[i]);
    float lm = fmaxf(lga, lgb);
    float ea = expf(lga - lm), eb = expf(lgb - lm);
    sample[i] = ea / (ea + eb);
}

__global__ void k_pis(const float* __restrict__ sample, float* __restrict__ pis) {
    int n = blockIdx.x * blockDim.x + threadIdx.x;
    if (n >= NROW) return;
    float rp = 1.0f;
    for (int e = 0; e < NEXP; ++e) {
        float s = sample[n * NEXP + e];
        pis[n * NEXP + e] = rp * s;
        rp = rp * (1.0f - s);
    }
}

// w = pis / Z on rows [r0, r0+cnt)   (fallback path only)
__global__ void k_w(const float* __restrict__ pis, const float* __restrict__ Z,
                    float* __restrict__ w, int r0, int cnt) {
    int i = blockIdx.x * 256 + threadIdx.x;
    if (i >= cnt) return;
    int r = r0 + i;
    w[r] = pis[r] / Z[r];
}

__global__ void k_cvt(const float* __restrict__ src, unsigned short* __restrict__ dst, int n) {
    int i = (blockIdx.x * 256 + threadIdx.x) * 8;
    if (i >= n) return;
    float4 v0 = *(const float4*)(src + i);
    float4 v1 = *(const float4*)(src + i + 4);
    us16x8 o;
    o[0] = f2b(v0.x); o[1] = f2b(v0.y); o[2] = f2b(v0.z); o[3] = f2b(v0.w);
    o[4] = f2b(v1.x); o[5] = f2b(v1.y); o[6] = f2b(v1.z); o[7] = f2b(v1.w);
    *(us16x8*)(dst + i) = o;
}

// ---------------------------------------------------------------------------
// Combine span: out[n0+nl, c8*8..] = sum_e (pis/Z) * P[nl*10+e, ...]
// P reads CACHED (P-chunk is L3-resident at CR=1280); out write non-temporal.
// ---------------------------------------------------------------------------
__device__ __forceinline__ void combine_span(const unsigned short* __restrict__ P,
                                             const float* __restrict__ pis,
                                             const float* __restrict__ Z,
                                             float* __restrict__ out,
                                             int n0, int items, int idx0, int stride) {
    for (int idx = idx0; idx < items; idx += stride) {
        int nl = idx / 4000;
        int c8 = (idx - nl * 4000) * 8;
        int n  = n0 + nl;
        float w[NEXP];
#pragma unroll
        for (int e = 0; e < NEXP; ++e)
            w[e] = pis[n * NEXP + e] / Z[n * NEXP + e];
        float s[8] = {0.f,0.f,0.f,0.f,0.f,0.f,0.f,0.f};
        const unsigned short* Pr = P + (size_t)nl * NEXP * NTOK + c8;
#pragma unroll
        for (int e = 0; e < NEXP; ++e) {
            us16x8 v = *(const us16x8*)(Pr + (size_t)e * NTOK);
#pragma unroll
            for (int jj = 0; jj < 8; ++jj)
                s[jj] = s[jj] + w[e] * b2f(v[jj]);
        }
        float* orow = out + (size_t)n * NTOK + c8;
        f32x4 o0 = {s[0], s[1], s[2], s[3]};
        f32x4 o1 = {s[4], s[5], s[6], s[7]};
        __builtin_nontemporal_store(o0, (f32x4*)(orow));
        __builtin_nontemporal_store(o1, (f32x4*)(orow + 4));
    }
}

__global__ __launch_bounds__(256)
void k_fin(const unsigned short* __restrict__ P,
           const float* __restrict__ pis,
           const float* __restrict__ Z,
           float* __restrict__ out, int n0, int items) {
    combine_span(P, pis, Z, out, n0, items,
                 (int)(blockIdx.x * 256u + threadIdx.x),
                 (int)(gridDim.x * 256u));
}

// ---------------------------------------------------------------------------
// Latent GEMM on MFMA: latb = bf16(tanh(outb[1024x1024] · wlatb^T + b_latent))
// XCD row-stripe swizzle; prefetch dbuf; unrolled K-loop, hoisted addressing.
// ---------------------------------------------------------------------------
__global__ __launch_bounds__(256)
void k_latm(const unsigned short* __restrict__ A,
            const unsigned short* __restrict__ B,
            const float* __restrict__ bias,
            unsigned short* __restrict__ dst) {
    __shared__ unsigned short Als[2][128 * 64];   // 2 x 16 KB
    __shared__ unsigned short Bls[2][128 * 64];   // 2 x 16 KB
    const int tid  = threadIdx.x;
    const int lane = tid & 63, wid = tid >> 6;
    const int wm = wid >> 1, wn = wid & 1;
    const uint32_t l = blockIdx.x;             // 320 = 8 xcd * 40 cols
    const int row0 = (int)(l & 7u) * 128;      // row-stripe per XCD
    const int col0 = (int)(l >> 3) * 128;
    const int lrow8 = lane >> 3, lslot = lane & 7;

    const unsigned short* pA[4];
    const unsigned short* pB[4];
#pragma unroll
    for (int i = 0; i < 4; ++i) {
        int rA = wid * 32 + i * 8 + lrow8;
        pA[i] = A + (size_t)(row0 + rA) * NHID + ((lslot ^ (rA & 7)) << 3);
        int rB = wid * 32 + i * 8 + lrow8;
        pB[i] = B + (size_t)(col0 + rB) * NHID + ((lslot ^ (rB & 7)) << 3);
    }
    int offA[2][4], offB[2][4];
#pragma unroll
    for (int kh = 0; kh < 2; ++kh)
#pragma unroll
        for (int f = 0; f < 4; ++f) {
            int rA = wm * 64 + f * 16 + (lane & 15);
            offA[kh][f] = rA * 128 + ((((lane >> 4) * 16) + kh * 64) ^ ((rA & 7) << 4));
            int rB = wn * 64 + f * 16 + (lane & 15);
            offB[kh][f] = rB * 128 + ((((lane >> 4) * 16) + kh * 64) ^ ((rB & 7) << 4));
        }

    f32x4 acc[4][4];
#pragma unroll
    for (int mf = 0; mf < 4; ++mf)
#pragma unroll
        for (int nf = 0; nf < 4; ++nf) acc[mf][nf] = (f32x4)0.f;

#pragma unroll
    for (int i = 0; i < 4; ++i) {
        GLD16(pA[i], (char*)&Als[0][0] + (wid * 32 + i * 8) * 128); pA[i] += 64;
        GLD16(pB[i], (char*)&Bls[0][0] + (wid * 32 + i * 8) * 128); pB[i] += 64;
    }
    __syncthreads();

#pragma unroll
    for (int t = 0; t < 16; ++t) {
        const int cur = t & 1, nxt = cur ^ 1;
        if (t < 15) {
#pragma unroll
            for (int i = 0; i < 4; ++i) {
                GLD16(pA[i], (char*)&Als[nxt][0] + (wid * 32 + i * 8) * 128); pA[i] += 64;
                GLD16(pB[i], (char*)&Bls[nxt][0] + (wid * 32 + i * 8) * 128); pB[i] += 64;
            }
        }
        const char* Ab = (const char*)&Als[cur][0];
        const char* Bb = (const char*)&Bls[cur][0];
#pragma unroll
        for (int kh = 0; kh < 2; ++kh) {
            bf16x8 af[4], bfr[4];
#pragma unroll
            for (int f = 0; f < 4; ++f) {
                af[f]  = *(const bf16x8*)(Ab + offA[kh][f]);
                bfr[f] = *(const bf16x8*)(Bb + offB[kh][f]);
            }
#pragma unroll
            for (int mf = 0; mf < 4; ++mf)
#pragma unroll
                for (int nf = 0; nf < 4; ++nf)
                    acc[mf][nf] = __builtin_amdgcn_mfma_f32_16x16x32_bf16(
                        af[mf], bfr[nf], acc[mf][nf], 0, 0, 0);
        }
        __syncthreads();               // per-wave vmcnt(0): prefetch landed
    }

    const int q = lane >> 4, cl = lane & 15;
#pragma unroll
    for (int mf = 0; mf < 4; ++mf) {
#pragma unroll
        for (int nf = 0; nf < 4; ++nf) {
            int col = col0 + wn * 64 + nf * 16 + cl;
            float bc = bias[col];
#pragma unroll
            for (int j = 0; j < 4; ++j) {
                int r = row0 + wm * 64 + mf * 16 + q * 4 + j;
                dst[(size_t)r * NLAT + col] = f2b(tanhf(acc[mf][nf][j] + bc));
            }
        }
    }
}

// ---------------------------------------------------------------------------
// MFMA decoder pass: prefetch dbuf (__syncthreads loop — verified round-15
// structure) + XCD stripe + hoisted addressing.
// tile 160x128, BK=64, 4 waves, 5x4 frags of 16x16x32.
// MODE 1: Z only  MODE 2: out=w*exp (fallback)
// MODE 3: Z + P-chunk via LDS-staged coalesced CACHED stores (stride 272 B)
// MODE 3 fused: blocks >= nGemm run combine_span for the PREVIOUS chunk.
// ---------------------------------------------------------------------------
template<int MODE>
__global__ __launch_bounds__(256)
void k_dec(const unsigned short* __restrict__ A,
           const unsigned short* __restrict__ B,
           const float* __restrict__ bias,
           const float* __restrict__ wmix,
           float* __restrict__ dst,
           unsigned short* __restrict__ Pst,
           int rb0, int nRB, int nGemm,
           const float* __restrict__ pis,
           const float* __restrict__ Zarr,
           float* __restrict__ outp,
           const unsigned short* __restrict__ Pprev,
           int n0prev, int itemsPrev) {
    if (MODE == 3 && (int)blockIdx.x >= nGemm) {
        const int cb = (int)blockIdx.x - nGemm;
        combine_span(Pprev, pis, Zarr, outp, n0prev, itemsPrev,
                     cb * 256 + (int)threadIdx.x,
                     ((int)gridDim.x - nGemm) * 256);
        return;
    }
    // unified LDS arena: [0,40960) = Als[2], [40960,73728) = Bls[2];
    // epilogue reuses [0, 160*272) as P staging (row stride 272 B, 16B-aligned)
    __shared__ __align__(16) unsigned char lds_raw[73728];
    unsigned short (*Als)[160 * 64] = (unsigned short (*)[160 * 64])lds_raw;
    unsigned short (*Bls)[128 * 64] = (unsigned short (*)[128 * 64])(lds_raw + 40960);
    const int tid  = threadIdx.x;
    const int lane = tid & 63, wid = tid >> 6;
    const int wm = wid >> 1, wn = wid & 1;
    const uint32_t l = blockIdx.x;
    int by_l, bx;
    if (nRB >= 8 && (nRB & 7) == 0) {  // XCD stripe: xcd = l%8 owns nRB/8 rows
        const int per = nRB >> 3;
        const uint32_t jb = l >> 3;
        by_l = (int)(l & 7u) * per + (int)(jb % (uint32_t)per);
        bx   = (int)(jb / (uint32_t)per);
    } else {
        by_l = (int)(l % (uint32_t)nRB);
        bx   = (int)(l / (uint32_t)nRB);
    }
    const int by   = rb0 + by_l;
    const int row0 = by * 160;
    const int rl0  = by_l * 160;       // P-local row base
    const int col0 = bx * 128;
    const int lrow8 = lane >> 3, lslot = lane & 7;

    const unsigned short* pA[5];
    const unsigned short* pB[4];
#pragma unroll
    for (int i = 0; i < 5; ++i) {
        int rA = wid * 40 + i * 8 + lrow8;
        pA[i] = A + (size_t)(row0 + rA) * 512 + ((lslot ^ (rA & 7)) << 3);
    }
#pragma unroll
    for (int i = 0; i < 4; ++i) {
        int rB = wid * 32 + i * 8 + lrow8;
        pB[i] = B + (size_t)(col0 + rB) * 512 + ((lslot ^ (rB & 7)) << 3);
    }
    int offA[2][5], offB[2][4];
#pragma unroll
    for (int kh = 0; kh < 2; ++kh) {
#pragma unroll
        for (int mf = 0; mf < 5; ++mf) {
            int r = wm * 80 + mf * 16 + (lane & 15);
            offA[kh][mf] = r * 128 + ((((lane >> 4) * 16) + kh * 64) ^ ((r & 7) << 4));
        }
#pragma unroll
        for (int nf = 0; nf < 4; ++nf) {
            int r = wn * 64 + nf * 16 + (lane & 15);
            offB[kh][nf] = r * 128 + ((((lane >> 4) * 16) + kh * 64) ^ ((r & 7) << 4));
        }
    }

    f32x4 acc[5][4];
#pragma unroll
    for (int mf = 0; mf < 5; ++mf)
#pragma unroll
        for (int nf = 0; nf < 4; ++nf) acc[mf][nf] = (f32x4)0.f;

    // prologue: tile 0 -> buf 0
#pragma unroll
    for (int i = 0; i < 5; ++i) {
        GLD16(pA[i], (char*)&Als[0][0] + (wid * 40 + i * 8) * 128); pA[i] += 64;
    }
#pragma unroll
    for (int i = 0; i < 4; ++i) {
        GLD16(pB[i], (char*)&Bls[0][0] + (wid * 32 + i * 8) * 128); pB[i] += 64;
    }
    __syncthreads();

#pragma unroll
    for (int t = 0; t < 8; ++t) {
        const int cur = t & 1, nxt = cur ^ 1;
        if (t < 7) {
#pragma unroll
            for (int i = 0; i < 5; ++i) {
                GLD16(pA[i], (char*)&Als[nxt][0] + (wid * 40 + i * 8) * 128); pA[i] += 64;
            }
#pragma unroll
            for (int i = 0; i < 4; ++i) {
                GLD16(pB[i], (char*)&Bls[nxt][0] + (wid * 32 + i * 8) * 128); pB[i] += 64;
            }
        }
        const char* Ab = (const char*)&Als[cur][0];
        const char* Bb = (const char*)&Bls[cur][0];
#pragma unroll
        for (int kh = 0; kh < 2; ++kh) {
            bf16x8 af[5], bfr[4];
#pragma unroll
            for (int mf = 0; mf < 5; ++mf)
                af[mf] = *(const bf16x8*)(Ab + offA[kh][mf]);
#pragma unroll
            for (int nf = 0; nf < 4; ++nf)
                bfr[nf] = *(const bf16x8*)(Bb + offB[kh][nf]);
#pragma unroll
            for (int mf = 0; mf < 5; ++mf)
#pragma unroll
                for (int nf = 0; nf < 4; ++nf)
                    acc[mf][nf] = __builtin_amdgcn_mfma_f32_16x16x32_bf16(
                        af[mf], bfr[nf], acc[mf][nf], 0, 0, 0);
        }
        __syncthreads();               // per-wave vmcnt(0): prefetch landed
    }

    // C layout per frag: row = (lane>>4)*4 + j, col = lane&15  [m89-verified]
    const int q = lane >> 4, cl = lane & 15;
    float bv[4];
#pragma unroll
    for (int nf = 0; nf < 4; ++nf) bv[nf] = bias[col0 + wn * 64 + nf * 16 + cl];

    if (MODE == 3) {
        // exp + Z atomics + stage P tile into LDS (row stride 272 B)
#pragma unroll
        for (int mf = 0; mf < 5; ++mf) {
#pragma unroll
            for (int jj = 0; jj < 4; ++jj) {
                const int rr = wm * 80 + mf * 16 + q * 4 + jj;
                float p0 = expf(acc[mf][0][jj] + bv[0]);
                float p1 = expf(acc[mf][1][jj] + bv[1]);
                float p2 = expf(acc[mf][2][jj] + bv[2]);
                float p3 = expf(acc[mf][3][jj] + bv[3]);
                float s = ((p0 + p1) + (p2 + p3));
                s += __shfl_xor(s, 1); s += __shfl_xor(s, 2);
                s += __shfl_xor(s, 4); s += __shfl_xor(s, 8);
                if (cl == 0) atomicAdd(&dst[row0 + rr], s);
                unsigned short* lrow = (unsigned short*)(lds_raw + rr * 272);
                lrow[wn * 64 + cl]      = f2b(p0);
                lrow[wn * 64 + 16 + cl] = f2b(p1);
                lrow[wn * 64 + 32 + cl] = f2b(p2);
                lrow[wn * 64 + 48 + cl] = f2b(p3);
            }
        }
        __syncthreads();
        // coalesced writeout (CACHED: P-chunk stays L3-resident for combine)
        const int rloc = tid >> 4, c16 = tid & 15;
#pragma unroll
        for (int it = 0; it < 10; ++it) {
            int gr = it * 16 + rloc;
            us16x8 v = *(const us16x8*)(lds_raw + gr * 272 + c16 * 16);
            *(us16x8*)(Pst + (size_t)(rl0 + gr) * NTOK + col0 + c16 * 8) = v;
        }
    } else if (MODE == 1) {
#pragma unroll
        for (int mf = 0; mf < 5; ++mf) {
#pragma unroll
            for (int jj = 0; jj < 4; ++jj) {
                const int rr = wm * 80 + mf * 16 + q * 4 + jj;
                float p0 = expf(acc[mf][0][jj] + bv[0]);
                float p1 = expf(acc[mf][1][jj] + bv[1]);
                float p2 = expf(acc[mf][2][jj] + bv[2]);
                float p3 = expf(acc[mf][3][jj] + bv[3]);
                float s = ((p0 + p1) + (p2 + p3));
                s += __shfl_xor(s, 1); s += __shfl_xor(s, 2);
                s += __shfl_xor(s, 4); s += __shfl_xor(s, 8);
                if (cl == 0) atomicAdd(&dst[row0 + rr], s);
            }
        }
    } else {
        float wv[5][4];
#pragma unroll
        for (int mf = 0; mf < 5; ++mf)
#pragma unroll
            for (int jj = 0; jj < 4; ++jj)
                wv[mf][jj] = wmix[row0 + wm * 80 + mf * 16 + q * 4 + jj];
#pragma unroll
        for (int mf = 0; mf < 5; ++mf)
#pragma unroll
            for (int nf = 0; nf < 4; ++nf)
#pragma unroll
                for (int jj = 0; jj < 4; ++jj)
                    acc[mf][nf][jj] = wv[mf][jj] * expf(acc[mf][nf][jj] + bv[nf]);

        const int tok0 = by * 16 + wm * 8;
#pragma unroll
        for (int t = 0; t < 8; ++t) {
#pragma unroll
            for (int nf = 0; nf < 4; ++nf) {
                float s = 0.f;
#pragma unroll
                for (int i = 0; i < 10; ++i) {
                    const int rl = 10 * t + i;
                    const int mf = rl >> 4, qr = (rl >> 2) & 3, jj = rl & 3;
                    s += (q == qr) ? acc[mf][nf][jj] : 0.f;
                }
                s += __shfl_xor(s, 16);
                s += __shfl_xor(s, 32);
                if (q == 0)
                    dst[(size_t)(tok0 + t) * NTOK + col0 + wn * 64 + nf * 16 + cl] = s;
            }
        }
    }
}

// ---------------------------------------------------------------------------
extern "C" void kernel_launch(void* const* d_in, const int* in_sizes, int n_in,
                              void* d_out, int out_size, void* d_ws, size_t ws_size,
                              hipStream_t stream) {
    const float* output    = (const float*)d_in[0];  // [1024,1024]
    const float* W_latent  = (const float*)d_in[1];  // [5120,1024]
    const float* b_latent  = (const float*)d_in[2];  // [5120]
    const float* W_decoder = (const float*)d_in[3];  // [32000,512]
    const float* b_decoder = (const float*)d_in[4];  // [32000]
    const float* W_reduce  = (const float*)d_in[5];  // [10,1024]
    const float* b_reduce  = (const float*)d_in[6];  // [10]
    float* out = (float*)d_out;                      // [1024,32000]

    // ws layout: latb(10.49MB) | wdecb(32.77MB) | 6x f32[MROWS] | P buffers
    char* wsb = (char*)d_ws;
    unsigned short* latb  = (unsigned short*)wsb;
    unsigned short* wdecb = (unsigned short*)(wsb + 10485760);
    float* a_arr  = (float*)(wsb + 10485760 + 32768000);
    float* dpar   = a_arr  + MROWS;
    float* sample = dpar   + MROWS;
    float* pis    = sample + MROWS;
    float* Z      = pis    + MROWS;
    float* wmix   = Z      + MROWS;
    unsigned short* Pbuf = (unsigned short*)(wmix + MROWS);
    const size_t BASE = 10485760ull + 32768000ull + 6ull * MROWS * 4ull;
    const size_t avail = (ws_size > BASE) ? (ws_size - BASE) : 0;

    // prefer CR=1280: double-P = 164 MB -> L3-resident, P never hits HBM
    int CRd = 0, CRs = 0;
    {
        const int cands[4] = {1280, 2560, 640, 320};
        for (int c = 0; c < 4; ++c)
            if (2ull * (size_t)cands[c] * NTOK * 2ull <= avail) { CRd = cands[c]; break; }
        if (CRd == 0) {
            const int cs[5] = {2560, 1280, 640, 320, 160};
            for (int c = 0; c < 5; ++c)
                if ((size_t)cs[c] * NTOK * 2ull <= avail) { CRs = cs[c]; break; }
        }
    }

    // bf16 copies of output/W_latent live in d_out (fully overwritten later)
    unsigned short* outb  = (unsigned short*)d_out;
    unsigned short* wlatb = (unsigned short*)((char*)d_out + 2097152);

    k_a<<<NROW, 64, 0, stream>>>(output, W_reduce, b_reduce, a_arr, dpar);
    k_sample<<<MROWS / 256, 256, 0, stream>>>(a_arr, dpar, sample);
    k_pis<<<(NROW + 255) / 256, 256, 0, stream>>>(sample, pis);

    k_cvt<<<(NTOK * NINP) / 2048, 256, 0, stream>>>(W_decoder, wdecb, NTOK * NINP);
    k_cvt<<<(NROW * NHID) / 2048, 256, 0, stream>>>(output, outb, NROW * NHID);
    k_cvt<<<(NLAT * NHID) / 2048, 256, 0, stream>>>(W_latent, wlatb, NLAT * NHID);

    k_latm<<<320, 256, 0, stream>>>(outb, wlatb, b_latent, latb);

    (void)hipMemsetAsync(Z, 0, MROWS * sizeof(float), stream);

    if (CRd > 0) {
        // fused path: GEMM(ci) + combine(ci-1) in one launch, double Pbuf.
        const int nRB = CRd / 160, nGemm = nRB * 250, nch = MROWS / CRd;
        const int items = (CRd / 10) * 4000;
        for (int ci = 0; ci < nch; ++ci) {
            unsigned short* Pcur  = Pbuf + (size_t)(ci & 1) * CRd * NTOK;
            unsigned short* Pprev = Pbuf + (size_t)((ci & 1) ^ 1) * CRd * NTOK;
            const int extra = (ci > 0) ? 1000 : 0;
            k_dec<3><<<nGemm + extra, 256, 0, stream>>>(
                latb, wdecb, b_decoder, nullptr, Z, Pcur, ci * nRB, nRB, nGemm,
                pis, Z, out, Pprev, (ci - 1) * (CRd / 10), items);
        }
        unsigned short* Plast = Pbuf + (size_t)((nch - 1) & 1) * CRd * NTOK;
        k_fin<<<items / 256, 256, 0, stream>>>(Plast, pis, Z, out,
                                               (nch - 1) * (CRd / 10), items);
    } else if (CRs > 0) {
        // single-buffer chunked path
        const int nRB = CRs / 160;
        const int items = (CRs / 10) * 4000;
        for (int r0 = 0; r0 < MROWS; r0 += CRs) {
            k_dec<3><<<nRB * 250, 256, 0, stream>>>(
                latb, wdecb, b_decoder, nullptr, Z, Pbuf, r0 / 160, nRB, 1 << 30,
                pis, Z, out, nullptr, 0, 0);
            k_fin<<<items / 256, 256, 0, stream>>>(Pbuf, pis, Z, out, r0 / 10, items);
        }
    } else {
        // fallback: two full GEMM passes
        k_dec<1><<<16000, 256, 0, stream>>>(latb, wdecb, b_decoder, nullptr, Z,
                                            nullptr, 0, 64, 1 << 30,
                                            pis, Z, out, nullptr, 0, 0);
        k_w<<<MROWS / 256, 256, 0, stream>>>(pis, Z, wmix, 0, MROWS);
        k_dec<2><<<16000, 256, 0, stream>>>(latb, wdecb, b_decoder, wmix, out,
                                            nullptr, 0, 64, 1 << 30,
                                            pis, Z, out, nullptr, 0, 0);
    }
    (void)in_sizes; (void)n_in; (void)out_size;
}

// Round 19
// 821.529 us; speedup vs baseline: 1.3666x; 1.3666x over previous
//
#include <hip/hip_runtime.h>
#include <cstdint>
#include <cstddef>

#pragma clang fp contract(off)

#define NTOK  32000
#define NINP  512
#define NHID  1024
#define NEXP  10
#define NROW  1024            // N (tokens)
#define NLAT  (NEXP*NINP)     // 5120
#define MROWS (NROW*NEXP)     // 10240

typedef __attribute__((ext_vector_type(4))) float f32x4;
typedef __attribute__((ext_vector_type(8))) short bf16x8;
typedef __attribute__((ext_vector_type(8))) unsigned short us16x8;

// async global->LDS, 16B per lane: LDS dest = wave-uniform base + lane*16
#define GLD16(g, l) __builtin_amdgcn_global_load_lds(                       \
    (const __attribute__((address_space(1))) void*)(g),                     \
    (__attribute__((address_space(3))) void*)(l), 16, 0, 0)

// f32 -> bf16 round-to-nearest-even
__device__ __forceinline__ unsigned short f2b(float x) {
    uint32_t u = __float_as_uint(x);
    uint32_t r = (u + 0x7fffu + ((u >> 16) & 1u)) >> 16;
    return (unsigned short)r;
}
__device__ __forceinline__ float b2f(unsigned short b) {
    return __uint_as_float(((uint32_t)b) << 16);
}

// ---------------------------------------------------------------------------
// threefry2x32 (JAX-exact)
// ---------------------------------------------------------------------------
__device__ __forceinline__ uint32_t rotl32(uint32_t v, int r) {
    return (v << r) | (v >> (32 - r));
}

__device__ __forceinline__ void threefry(uint32_t k0, uint32_t k1,
                                         uint32_t x0, uint32_t x1,
                                         uint32_t& o0, uint32_t& o1) {
    uint32_t k2 = k0 ^ k1 ^ 0x1BD11BDAu;
    x0 += k0; x1 += k1;
#define TF_R(r) { x0 += x1; x1 = rotl32(x1, r); x1 ^= x0; }
    TF_R(13) TF_R(15) TF_R(26) TF_R(6)
    x0 += k1; x1 += k2 + 1u;
    TF_R(17) TF_R(29) TF_R(16) TF_R(24)
    x0 += k2; x1 += k0 + 2u;
    TF_R(13) TF_R(15) TF_R(26) TF_R(6)
    x0 += k0; x1 += k1 + 3u;
    TF_R(17) TF_R(29) TF_R(16) TF_R(24)
    x0 += k1; x1 += k2 + 4u;
    TF_R(13) TF_R(15) TF_R(26) TF_R(6)
    x0 += k2; x1 += k0 + 5u;
#undef TF_R
    o0 = x0; o1 = x1;
}

struct RKey { uint32_t a, b; };

__device__ __forceinline__ RKey kfold(RKey k, uint32_t i) {
    RKey r; threefry(k.a, k.b, 0u, i, r.a, r.b); return r;
}
__device__ __forceinline__ uint32_t kbits(RKey k) {
    uint32_t o0, o1; threefry(k.a, k.b, 0u, 0u, o0, o1); return o0 ^ o1;
}
__device__ __forceinline__ float u01(RKey k) {
    uint32_t b = (kbits(k) >> 9) | 0x3f800000u;
    return __uint_as_float(b) - 1.0f;
}
__device__ __forceinline__ float erfinv_xla(float x) {
    float xx = x * x;
    float w = -log1pf(-xx);
    float p;
    if (w < 5.0f) {
        float ww = w - 2.5f;
        p = 2.81022636e-08f;
        p = p * ww; p = p + 3.43273939e-07f;
        p = p * ww; p = p + -3.5233877e-06f;
        p = p * ww; p = p + -4.39150654e-06f;
        p = p * ww; p = p + 0.00021858087f;
        p = p * ww; p = p + -0.00125372503f;
        p = p * ww; p = p + -0.00417768164f;
        p = p * ww; p = p + 0.246640727f;
        p = p * ww; p = p + 1.50140941f;
    } else {
        float ww = sqrtf(w) - 3.0f;
        p = -0.000200214257f;
        p = p * ww; p = p + 0.000100950558f;
        p = p * ww; p = p + 0.00134934322f;
        p = p * ww; p = p + -0.00367342844f;
        p = p * ww; p = p + 0.00573950773f;
        p = p * ww; p = p + -0.0076224613f;
        p = p * ww; p = p + 0.00943887047f;
        p = p * ww; p = p + 1.00167406f;
        p = p * ww; p = p + 2.83297682f;
    }
    return p * x;
}
__device__ __forceinline__ float norm1(RKey k) {
    const float lo = -0.99999994f;
    float f = u01(k);
    float u = f * 2.0f;
    u = u + lo;
    u = fmaxf(lo, u);
    return 1.41421356f * erfinv_xla(u);
}

__device__ float gamma_log(RKey key, float alpha) {
    const float one_third = 0.33333334f;
    bool boost = (alpha >= 1.0f);
    float alpha_orig = alpha;
    if (!boost) alpha = alpha + 1.0f;
    float d = alpha - one_third;
    float c = one_third / sqrtf(d);

    RKey sub = kfold(key, 1u);
    key      = kfold(key, 0u);
    float log_boost = 0.0f;
    if (!boost) {
        float uB = u01(sub);
        log_boost = log1pf(-uB) * (1.0f / alpha_orig);
    }

    float X = 0.f, V = 1.f, U = 2.f;
    int guard = 0;
    do {
        RKey xk = kfold(key, 1u);
        RKey Uk = kfold(key, 2u);
        key     = kfold(key, 0u);
        float x = 0.f, v = -1.f;
        RKey kin = xk;
        int g2 = 0;
        do {
            RKey sk = kfold(kin, 1u);
            kin     = kfold(kin, 0u);
            x = norm1(sk);
            float cx = x * c;
            v = 1.0f + cx;
        } while (v <= 0.0f && ++g2 < 256);
        X = x * x;
        V = (v * v) * v;
        U = u01(Uk);
        float sq = 1.0f - 0.0331f * (X * X);
        if (U < sq) break;
        float bound = (X * 0.5f) + ((d - d * V) + d * logf(V));
        if (logf(U) < bound) break;
    } while (++guard < 256);

    float ls = logf(d) + logf(V);
    ls = ls + log_boost;
    return ls;
}

// ---------------------------------------------------------------------------
__global__ void k_a(const float* __restrict__ out_in,
                    const float* __restrict__ Wred,
                    const float* __restrict__ bred,
                    float* __restrict__ a_arr, float* __restrict__ dpar) {
    int n = blockIdx.x;
    int lane = threadIdx.x;
    __shared__ float zred[NEXP];
    const float* orow = out_in + (size_t)n * NHID;
    for (int e = 0; e < NEXP; ++e) {
        const float* wrow = Wred + (size_t)e * NHID;
        float s = 0.f;
        for (int k = lane; k < NHID; k += 64) s += orow[k] * wrow[k];
        for (int off = 32; off; off >>= 1) s += __shfl_xor(s, off);
        if (lane == 0) zred[e] = s + bred[e];
    }
    __syncthreads();
    if (lane == 0) {
        float a[NEXP];
        float b = 0.f;
        for (int e = 0; e < NEXP; ++e) {
            float z = zred[e];
            a[e] = fmaxf(z, 0.f) + log1pf(expf(-fabsf(z))) + 1e-8f;
        }
        for (int e = 0; e < NEXP; ++e) b += a[e];
        float cs = 0.f;
        for (int e = 0; e < NEXP; ++e) {
            cs += a[e];
            float dd = fmaxf(fabsf(b - cs), 1e-8f);
            a_arr[n * NEXP + e] = a[e];
            dpar [n * NEXP + e] = dd;
        }
    }
}

__global__ void k_sample(const float* __restrict__ a_arr,
                         const float* __restrict__ dpar,
                         float* __restrict__ sample) {
    int i = blockIdx.x * 256 + threadIdx.x;
    if (i >= MROWS) return;
    RKey root{0u, 42u};
    RKey ka = kfold(root, 0u);
    RKey kb = kfold(root, 1u);
    float lga = gamma_log(kfold(ka, (uint32_t)i), a_arr[i]);
    float lgb = gamma_log(kfold(kb, (uint32_t)i), dpar[i]);
    float lm = fmaxf(lga, lgb);
    float ea = expf(lga - lm), eb = expf(lgb - lm);
    sample[i] = ea / (ea + eb);
}

__global__ void k_pis(const float* __restrict__ sample, float* __restrict__ pis) {
    int n = blockIdx.x * blockDim.x + threadIdx.x;
    if (n >= NROW) return;
    float rp = 1.0f;
    for (int e = 0; e < NEXP; ++e) {
        float s = sample[n * NEXP + e];
        pis[n * NEXP + e] = rp * s;
        rp = rp * (1.0f - s);
    }
}

// w = pis / Z on rows [r0, r0+cnt)   (fallback path only)
__global__ void k_w(const float* __restrict__ pis, const float* __restrict__ Z,
                    float* __restrict__ w, int r0, int cnt) {
    int i = blockIdx.x * 256 + threadIdx.x;
    if (i >= cnt) return;
    int r = r0 + i;
    w[r] = pis[r] / Z[r];
}

__global__ void k_cvt(const float* __restrict__ src, unsigned short* __restrict__ dst, int n) {
    int i = (blockIdx.x * 256 + threadIdx.x) * 8;
    if (i >= n) return;
    float4 v0 = *(const float4*)(src + i);
    float4 v1 = *(const float4*)(src + i + 4);
    us16x8 o;
    o[0] = f2b(v0.x); o[1] = f2b(v0.y); o[2] = f2b(v0.z); o[3] = f2b(v0.w);
    o[4] = f2b(v1.x); o[5] = f2b(v1.y); o[6] = f2b(v1.z); o[7] = f2b(v1.w);
    *(us16x8*)(dst + i) = o;
}

// ---------------------------------------------------------------------------
// Combine span: out[n0+nl, c8*8..] = sum_e (pis/Z) * P[nl*10+e, ...]
// P read + out write are non-temporal (write/read-once streams; keep L3 for B)
// ---------------------------------------------------------------------------
__device__ __forceinline__ void combine_span(const unsigned short* __restrict__ P,
                                             const float* __restrict__ pis,
                                             const float* __restrict__ Z,
                                             float* __restrict__ out,
                                             int n0, int items, int idx0, int stride) {
    for (int idx = idx0; idx < items; idx += stride) {
        int nl = idx / 4000;
        int c8 = (idx - nl * 4000) * 8;
        int n  = n0 + nl;
        float w[NEXP];
#pragma unroll
        for (int e = 0; e < NEXP; ++e)
            w[e] = pis[n * NEXP + e] / Z[n * NEXP + e];
        float s[8] = {0.f,0.f,0.f,0.f,0.f,0.f,0.f,0.f};
        const unsigned short* Pr = P + (size_t)nl * NEXP * NTOK + c8;
#pragma unroll
        for (int e = 0; e < NEXP; ++e) {
            us16x8 v = __builtin_nontemporal_load((const us16x8*)(Pr + (size_t)e * NTOK));
#pragma unroll
            for (int jj = 0; jj < 8; ++jj)
                s[jj] = s[jj] + w[e] * b2f(v[jj]);
        }
        float* orow = out + (size_t)n * NTOK + c8;
        f32x4 o0 = {s[0], s[1], s[2], s[3]};
        f32x4 o1 = {s[4], s[5], s[6], s[7]};
        __builtin_nontemporal_store(o0, (f32x4*)(orow));
        __builtin_nontemporal_store(o1, (f32x4*)(orow + 4));
    }
}

__global__ __launch_bounds__(256)
void k_fin(const unsigned short* __restrict__ P,
           const float* __restrict__ pis,
           const float* __restrict__ Z,
           float* __restrict__ out, int n0, int items) {
    combine_span(P, pis, Z, out, n0, items,
                 (int)(blockIdx.x * 256u + threadIdx.x),
                 (int)(gridDim.x * 256u));
}

// ---------------------------------------------------------------------------
// Latent GEMM on MFMA: latb = bf16(tanh(outb[1024x1024] · wlatb^T + b_latent))
// XCD row-stripe swizzle; prefetch dbuf; unrolled K-loop, hoisted addressing.
// ---------------------------------------------------------------------------
__global__ __launch_bounds__(256)
void k_latm(const unsigned short* __restrict__ A,
            const unsigned short* __restrict__ B,
            const float* __restrict__ bias,
            unsigned short* __restrict__ dst) {
    __shared__ unsigned short Als[2][128 * 64];   // 2 x 16 KB
    __shared__ unsigned short Bls[2][128 * 64];   // 2 x 16 KB
    const int tid  = threadIdx.x;
    const int lane = tid & 63, wid = tid >> 6;
    const int wm = wid >> 1, wn = wid & 1;
    const uint32_t l = blockIdx.x;             // 320 = 8 xcd * 40 cols
    const int row0 = (int)(l & 7u) * 128;      // row-stripe per XCD
    const int col0 = (int)(l >> 3) * 128;
    const int lrow8 = lane >> 3, lslot = lane & 7;

    const unsigned short* pA[4];
    const unsigned short* pB[4];
#pragma unroll
    for (int i = 0; i < 4; ++i) {
        int rA = wid * 32 + i * 8 + lrow8;
        pA[i] = A + (size_t)(row0 + rA) * NHID + ((lslot ^ (rA & 7)) << 3);
        int rB = wid * 32 + i * 8 + lrow8;
        pB[i] = B + (size_t)(col0 + rB) * NHID + ((lslot ^ (rB & 7)) << 3);
    }
    int offA[2][4], offB[2][4];
#pragma unroll
    for (int kh = 0; kh < 2; ++kh)
#pragma unroll
        for (int f = 0; f < 4; ++f) {
            int rA = wm * 64 + f * 16 + (lane & 15);
            offA[kh][f] = rA * 128 + ((((lane >> 4) * 16) + kh * 64) ^ ((rA & 7) << 4));
            int rB = wn * 64 + f * 16 + (lane & 15);
            offB[kh][f] = rB * 128 + ((((lane >> 4) * 16) + kh * 64) ^ ((rB & 7) << 4));
        }

    f32x4 acc[4][4];
#pragma unroll
    for (int mf = 0; mf < 4; ++mf)
#pragma unroll
        for (int nf = 0; nf < 4; ++nf) acc[mf][nf] = (f32x4)0.f;

#pragma unroll
    for (int i = 0; i < 4; ++i) {
        GLD16(pA[i], (char*)&Als[0][0] + (wid * 32 + i * 8) * 128); pA[i] += 64;
        GLD16(pB[i], (char*)&Bls[0][0] + (wid * 32 + i * 8) * 128); pB[i] += 64;
    }
    __syncthreads();

#pragma unroll
    for (int t = 0; t < 16; ++t) {
        const int cur = t & 1, nxt = cur ^ 1;
        if (t < 15) {
#pragma unroll
            for (int i = 0; i < 4; ++i) {
                GLD16(pA[i], (char*)&Als[nxt][0] + (wid * 32 + i * 8) * 128); pA[i] += 64;
                GLD16(pB[i], (char*)&Bls[nxt][0] + (wid * 32 + i * 8) * 128); pB[i] += 64;
            }
        }
        const char* Ab = (const char*)&Als[cur][0];
        const char* Bb = (const char*)&Bls[cur][0];
#pragma unroll
        for (int kh = 0; kh < 2; ++kh) {
            bf16x8 af[4], bfr[4];
#pragma unroll
            for (int f = 0; f < 4; ++f) {
                af[f]  = *(const bf16x8*)(Ab + offA[kh][f]);
                bfr[f] = *(const bf16x8*)(Bb + offB[kh][f]);
            }
#pragma unroll
            for (int mf = 0; mf < 4; ++mf)
#pragma unroll
                for (int nf = 0; nf < 4; ++nf)
                    acc[mf][nf] = __builtin_amdgcn_mfma_f32_16x16x32_bf16(
                        af[mf], bfr[nf], acc[mf][nf], 0, 0, 0);
        }
        __syncthreads();               // per-wave vmcnt(0): prefetch landed
    }

    const int q = lane >> 4, cl = lane & 15;
#pragma unroll
    for (int mf = 0; mf < 4; ++mf) {
#pragma unroll
        for (int nf = 0; nf < 4; ++nf) {
            int col = col0 + wn * 64 + nf * 16 + cl;
            float bc = bias[col];
#pragma unroll
            for (int j = 0; j < 4; ++j) {
                int r = row0 + wm * 64 + mf * 16 + q * 4 + j;
                dst[(size_t)r * NLAT + col] = f2b(tanhf(acc[mf][nf][j] + bc));
            }
        }
    }
}

// ---------------------------------------------------------------------------
// MFMA decoder pass: prefetch dbuf (__syncthreads loop — verified round-15
// structure) + XCD stripe + hoisted addressing.
// tile 160x128, BK=64, 4 waves, 5x4 frags of 16x16x32.
// MODE 1: Z only  MODE 2: out=w*exp (fallback)
// MODE 3: Z + P-chunk via LDS-staged coalesced nt-stores (stride 272 B)
// MODE 3 fused: blocks >= nGemm run combine_span for the PREVIOUS chunk.
// ---------------------------------------------------------------------------
template<int MODE>
__global__ __launch_bounds__(256)
void k_dec(const unsigned short* __restrict__ A,
           const unsigned short* __restrict__ B,
           const float* __restrict__ bias,
           const float* __restrict__ wmix,
           float* __restrict__ dst,
           unsigned short* __restrict__ Pst,
           int rb0, int nRB, int nGemm,
           const float* __restrict__ pis,
           const float* __restrict__ Zarr,
           float* __restrict__ outp,
           const unsigned short* __restrict__ Pprev,
           int n0prev, int itemsPrev) {
    if (MODE == 3 && (int)blockIdx.x >= nGemm) {
        const int cb = (int)blockIdx.x - nGemm;
        combine_span(Pprev, pis, Zarr, outp, n0prev, itemsPrev,
                     cb * 256 + (int)threadIdx.x,
                     ((int)gridDim.x - nGemm) * 256);
        return;
    }
    // unified LDS arena: [0,40960) = Als[2], [40960,73728) = Bls[2];
    // epilogue reuses [0, 160*272) as P staging (row stride 272 B, 16B-aligned)
    __shared__ __align__(16) unsigned char lds_raw[73728];
    unsigned short (*Als)[160 * 64] = (unsigned short (*)[160 * 64])lds_raw;
    unsigned short (*Bls)[128 * 64] = (unsigned short (*)[128 * 64])(lds_raw + 40960);
    const int tid  = threadIdx.x;
    const int lane = tid & 63, wid = tid >> 6;
    const int wm = wid >> 1, wn = wid & 1;
    const uint32_t l = blockIdx.x;
    int by_l, bx;
    if (nRB >= 8 && (nRB & 7) == 0) {  // XCD stripe: xcd = l%8 owns nRB/8 rows
        const int per = nRB >> 3;
        const uint32_t jb = l >> 3;
        by_l = (int)(l & 7u) * per + (int)(jb % (uint32_t)per);
        bx   = (int)(jb / (uint32_t)per);
    } else {
        by_l = (int)(l % (uint32_t)nRB);
        bx   = (int)(l / (uint32_t)nRB);
    }
    const int by   = rb0 + by_l;
    const int row0 = by * 160;
    const int rl0  = by_l * 160;       // P-local row base
    const int col0 = bx * 128;
    const int lrow8 = lane >> 3, lslot = lane & 7;

    const unsigned short* pA[5];
    const unsigned short* pB[4];
#pragma unroll
    for (int i = 0; i < 5; ++i) {
        int rA = wid * 40 + i * 8 + lrow8;
        pA[i] = A + (size_t)(row0 + rA) * 512 + ((lslot ^ (rA & 7)) << 3);
    }
#pragma unroll
    for (int i = 0; i < 4; ++i) {
        int rB = wid * 32 + i * 8 + lrow8;
        pB[i] = B + (size_t)(col0 + rB) * 512 + ((lslot ^ (rB & 7)) << 3);
    }
    int offA[2][5], offB[2][4];
#pragma unroll
    for (int kh = 0; kh < 2; ++kh) {
#pragma unroll
        for (int mf = 0; mf < 5; ++mf) {
            int r = wm * 80 + mf * 16 + (lane & 15);
            offA[kh][mf] = r * 128 + ((((lane >> 4) * 16) + kh * 64) ^ ((r & 7) << 4));
        }
#pragma unroll
        for (int nf = 0; nf < 4; ++nf) {
            int r = wn * 64 + nf * 16 + (lane & 15);
            offB[kh][nf] = r * 128 + ((((lane >> 4) * 16) + kh * 64) ^ ((r & 7) << 4));
        }
    }

    f32x4 acc[5][4];
#pragma unroll
    for (int mf = 0; mf < 5; ++mf)
#pragma unroll
        for (int nf = 0; nf < 4; ++nf) acc[mf][nf] = (f32x4)0.f;

    // prologue: tile 0 -> buf 0
#pragma unroll
    for (int i = 0; i < 5; ++i) {
        GLD16(pA[i], (char*)&Als[0][0] + (wid * 40 + i * 8) * 128); pA[i] += 64;
    }
#pragma unroll
    for (int i = 0; i < 4; ++i) {
        GLD16(pB[i], (char*)&Bls[0][0] + (wid * 32 + i * 8) * 128); pB[i] += 64;
    }
    __syncthreads();

#pragma unroll
    for (int t = 0; t < 8; ++t) {
        const int cur = t & 1, nxt = cur ^ 1;
        if (t < 7) {
#pragma unroll
            for (int i = 0; i < 5; ++i) {
                GLD16(pA[i], (char*)&Als[nxt][0] + (wid * 40 + i * 8) * 128); pA[i] += 64;
            }
#pragma unroll
            for (int i = 0; i < 4; ++i) {
                GLD16(pB[i], (char*)&Bls[nxt][0] + (wid * 32 + i * 8) * 128); pB[i] += 64;
            }
        }
        const char* Ab = (const char*)&Als[cur][0];
        const char* Bb = (const char*)&Bls[cur][0];
#pragma unroll
        for (int kh = 0; kh < 2; ++kh) {
            bf16x8 af[5], bfr[4];
#pragma unroll
            for (int mf = 0; mf < 5; ++mf)
                af[mf] = *(const bf16x8*)(Ab + offA[kh][mf]);
#pragma unroll
            for (int nf = 0; nf < 4; ++nf)
                bfr[nf] = *(const bf16x8*)(Bb + offB[kh][nf]);
#pragma unroll
            for (int mf = 0; mf < 5; ++mf)
#pragma unroll
                for (int nf = 0; nf < 4; ++nf)
                    acc[mf][nf] = __builtin_amdgcn_mfma_f32_16x16x32_bf16(
                        af[mf], bfr[nf], acc[mf][nf], 0, 0, 0);
        }
        __syncthreads();               // per-wave vmcnt(0): prefetch landed
    }

    // C layout per frag: row = (lane>>4)*4 + j, col = lane&15  [m89-verified]
    const int q = lane >> 4, cl = lane & 15;
    float bv[4];
#pragma unroll
    for (int nf = 0; nf < 4; ++nf) bv[nf] = bias[col0 + wn * 64 + nf * 16 + cl];

    if (MODE == 3) {
        // exp + Z atomics + stage P tile into LDS (row stride 272 B)
#pragma unroll
        for (int mf = 0; mf < 5; ++mf) {
#pragma unroll
            for (int jj = 0; jj < 4; ++jj) {
                const int rr = wm * 80 + mf * 16 + q * 4 + jj;
                float p0 = expf(acc[mf][0][jj] + bv[0]);
                float p1 = expf(acc[mf][1][jj] + bv[1]);
                float p2 = expf(acc[mf][2][jj] + bv[2]);
                float p3 = expf(acc[mf][3][jj] + bv[3]);
                float s = ((p0 + p1) + (p2 + p3));
                s += __shfl_xor(s, 1); s += __shfl_xor(s, 2);
                s += __shfl_xor(s, 4); s += __shfl_xor(s, 8);
                if (cl == 0) atomicAdd(&dst[row0 + rr], s);
                unsigned short* lrow = (unsigned short*)(lds_raw + rr * 272);
                lrow[wn * 64 + cl]      = f2b(p0);
                lrow[wn * 64 + 16 + cl] = f2b(p1);
                lrow[wn * 64 + 32 + cl] = f2b(p2);
                lrow[wn * 64 + 48 + cl] = f2b(p3);
            }
        }
        __syncthreads();
        // coalesced writeout: 256 threads = 16 rows x 16 lanes, 10 passes
        const int rloc = tid >> 4, c16 = tid & 15;
#pragma unroll
        for (int it = 0; it < 10; ++it) {
            int gr = it * 16 + rloc;
            us16x8 v = *(const us16x8*)(lds_raw + gr * 272 + c16 * 16);
            __builtin_nontemporal_store(
                v, (us16x8*)(Pst + (size_t)(rl0 + gr) * NTOK + col0 + c16 * 8));
        }
    } else if (MODE == 1) {
#pragma unroll
        for (int mf = 0; mf < 5; ++mf) {
#pragma unroll
            for (int jj = 0; jj < 4; ++jj) {
                const int rr = wm * 80 + mf * 16 + q * 4 + jj;
                float p0 = expf(acc[mf][0][jj] + bv[0]);
                float p1 = expf(acc[mf][1][jj] + bv[1]);
                float p2 = expf(acc[mf][2][jj] + bv[2]);
                float p3 = expf(acc[mf][3][jj] + bv[3]);
                float s = ((p0 + p1) + (p2 + p3));
                s += __shfl_xor(s, 1); s += __shfl_xor(s, 2);
                s += __shfl_xor(s, 4); s += __shfl_xor(s, 8);
                if (cl == 0) atomicAdd(&dst[row0 + rr], s);
            }
        }
    } else {
        float wv[5][4];
#pragma unroll
        for (int mf = 0; mf < 5; ++mf)
#pragma unroll
            for (int jj = 0; jj < 4; ++jj)
                wv[mf][jj] = wmix[row0 + wm * 80 + mf * 16 + q * 4 + jj];
#pragma unroll
        for (int mf = 0; mf < 5; ++mf)
#pragma unroll
            for (int nf = 0; nf < 4; ++nf)
#pragma unroll
                for (int jj = 0; jj < 4; ++jj)
                    acc[mf][nf][jj] = wv[mf][jj] * expf(acc[mf][nf][jj] + bv[nf]);

        const int tok0 = by * 16 + wm * 8;
#pragma unroll
        for (int t = 0; t < 8; ++t) {
#pragma unroll
            for (int nf = 0; nf < 4; ++nf) {
                float s = 0.f;
#pragma unroll
                for (int i = 0; i < 10; ++i) {
                    const int rl = 10 * t + i;
                    const int mf = rl >> 4, qr = (rl >> 2) & 3, jj = rl & 3;
                    s += (q == qr) ? acc[mf][nf][jj] : 0.f;
                }
                s += __shfl_xor(s, 16);
                s += __shfl_xor(s, 32);
                if (q == 0)
                    dst[(size_t)(tok0 + t) * NTOK + col0 + wn * 64 + nf * 16 + cl] = s;
            }
        }
    }
}

// ---------------------------------------------------------------------------
extern "C" void kernel_launch(void* const* d_in, const int* in_sizes, int n_in,
                              void* d_out, int out_size, void* d_ws, size_t ws_size,
                              hipStream_t stream) {
    const float* output    = (const float*)d_in[0];  // [1024,1024]
    const float* W_latent  = (const float*)d_in[1];  // [5120,1024]
    const float* b_latent  = (const float*)d_in[2];  // [5120]
    const float* W_decoder = (const float*)d_in[3];  // [32000,512]
    const float* b_decoder = (const float*)d_in[4];  // [32000]
    const float* W_reduce  = (const float*)d_in[5];  // [10,1024]
    const float* b_reduce  = (const float*)d_in[6];  // [10]
    float* out = (float*)d_out;                      // [1024,32000]

    // ws layout: latb(10.49MB) | wdecb(32.77MB) | 6x f32[MROWS] | P buffers
    char* wsb = (char*)d_ws;
    unsigned short* latb  = (unsigned short*)wsb;
    unsigned short* wdecb = (unsigned short*)(wsb + 10485760);
    float* a_arr  = (float*)(wsb + 10485760 + 32768000);
    float* dpar   = a_arr  + MROWS;
    float* sample = dpar   + MROWS;
    float* pis    = sample + MROWS;
    float* Z      = pis    + MROWS;
    float* wmix   = Z      + MROWS;
    unsigned short* Pbuf = (unsigned short*)(wmix + MROWS);
    const size_t BASE = 10485760ull + 32768000ull + 6ull * MROWS * 4ull;
    const size_t avail = (ws_size > BASE) ? (ws_size - BASE) : 0;

    // choose: double-buffered chunk (fused combine) > single chunk > fallback
    int CRd = 0, CRs = 0;
    {
        const int cands[4] = {2560, 1280, 640, 320};
        for (int c = 0; c < 4; ++c)
            if (2ull * (size_t)cands[c] * NTOK * 2ull <= avail) { CRd = cands[c]; break; }
        if (CRd == 0) {
            const int cs[5] = {2560, 1280, 640, 320, 160};
            for (int c = 0; c < 5; ++c)
                if ((size_t)cs[c] * NTOK * 2ull <= avail) { CRs = cs[c]; break; }
        }
    }

    // bf16 copies of output/W_latent live in d_out (fully overwritten later)
    unsigned short* outb  = (unsigned short*)d_out;
    unsigned short* wlatb = (unsigned short*)((char*)d_out + 2097152);

    k_a<<<NROW, 64, 0, stream>>>(output, W_reduce, b_reduce, a_arr, dpar);
    k_sample<<<MROWS / 256, 256, 0, stream>>>(a_arr, dpar, sample);
    k_pis<<<(NROW + 255) / 256, 256, 0, stream>>>(sample, pis);

    k_cvt<<<(NTOK * NINP) / 2048, 256, 0, stream>>>(W_decoder, wdecb, NTOK * NINP);
    k_cvt<<<(NROW * NHID) / 2048, 256, 0, stream>>>(output, outb, NROW * NHID);
    k_cvt<<<(NLAT * NHID) / 2048, 256, 0, stream>>>(W_latent, wlatb, NLAT * NHID);

    k_latm<<<320, 256, 0, stream>>>(outb, wlatb, b_latent, latb);

    (void)hipMemsetAsync(Z, 0, MROWS * sizeof(float), stream);

    if (CRd > 0) {
        // fused path: GEMM(ci) + combine(ci-1) in one launch, double Pbuf.
        const int nRB = CRd / 160, nGemm = nRB * 250, nch = MROWS / CRd;
        const int items = (CRd / 10) * 4000;
        for (int ci = 0; ci < nch; ++ci) {
            unsigned short* Pcur  = Pbuf + (size_t)(ci & 1) * CRd * NTOK;
            unsigned short* Pprev = Pbuf + (size_t)((ci & 1) ^ 1) * CRd * NTOK;
            const int extra = (ci > 0) ? 1000 : 0;
            k_dec<3><<<nGemm + extra, 256, 0, stream>>>(
                latb, wdecb, b_decoder, nullptr, Z, Pcur, ci * nRB, nRB, nGemm,
                pis, Z, out, Pprev, (ci - 1) * (CRd / 10), items);
        }
        unsigned short* Plast = Pbuf + (size_t)((nch - 1) & 1) * CRd * NTOK;
        k_fin<<<items / 256, 256, 0, stream>>>(Plast, pis, Z, out,
                                               (nch - 1) * (CRd / 10), items);
    } else if (CRs > 0) {
        // single-buffer chunked path
        const int nRB = CRs / 160;
        const int items = (CRs / 10) * 4000;
        for (int r0 = 0; r0 < MROWS; r0 += CRs) {
            k_dec<3><<<nRB * 250, 256, 0, stream>>>(
                latb, wdecb, b_decoder, nullptr, Z, Pbuf, r0 / 160, nRB, 1 << 30,
                pis, Z, out, nullptr, 0, 0);
            k_fin<<<items / 256, 256, 0, stream>>>(Pbuf, pis, Z, out, r0 / 10, items);
        }
    } else {
        // fallback: two full GEMM passes
        k_dec<1><<<16000, 256, 0, stream>>>(latb, wdecb, b_decoder, nullptr, Z,
                                            nullptr, 0, 64, 1 << 30,
                                            pis, Z, out, nullptr, 0, 0);
        k_w<<<MROWS / 256, 256, 0, stream>>>(pis, Z, wmix, 0, MROWS);
        k_dec<2><<<16000, 256, 0, stream>>>(latb, wdecb, b_decoder, wmix, out,
                                            nullptr, 0, 64, 1 << 30,
                                            pis, Z, out, nullptr, 0, 0);
    }
    (void)in_sizes; (void)n_in; (void)out_size;
}

// Round 20
// 800.807 us; speedup vs baseline: 1.4020x; 1.0259x over previous
//
#include <hip/hip_runtime.h>
#include <cstdint>
#include <cstddef>

#pragma clang fp contract(off)

#define NTOK  32000
#define NINP  512
#define NHID  1024
#define NEXP  10
#define NROW  1024            // N (tokens)
#define NLAT  (NEXP*NINP)     // 5120
#define MROWS (NROW*NEXP)     // 10240

typedef __attribute__((ext_vector_type(4))) float f32x4;
typedef __attribute__((ext_vector_type(8))) short bf16x8;
typedef __attribute__((ext_vector_type(8))) unsigned short us16x8;

// async global->LDS, 16B per lane: LDS dest = wave-uniform base + lane*16
#define GLD16(g, l) __builtin_amdgcn_global_load_lds(                       \
    (const __attribute__((address_space(1))) void*)(g),                     \
    (__attribute__((address_space(3))) void*)(l), 16, 0, 0)

// f32 -> bf16 round-to-nearest-even
__device__ __forceinline__ unsigned short f2b(float x) {
    uint32_t u = __float_as_uint(x);
    uint32_t r = (u + 0x7fffu + ((u >> 16) & 1u)) >> 16;
    return (unsigned short)r;
}
__device__ __forceinline__ float b2f(unsigned short b) {
    return __uint_as_float(((uint32_t)b) << 16);
}

// ---------------------------------------------------------------------------
// threefry2x32 (JAX-exact)
// ---------------------------------------------------------------------------
__device__ __forceinline__ uint32_t rotl32(uint32_t v, int r) {
    return (v << r) | (v >> (32 - r));
}

__device__ __forceinline__ void threefry(uint32_t k0, uint32_t k1,
                                         uint32_t x0, uint32_t x1,
                                         uint32_t& o0, uint32_t& o1) {
    uint32_t k2 = k0 ^ k1 ^ 0x1BD11BDAu;
    x0 += k0; x1 += k1;
#define TF_R(r) { x0 += x1; x1 = rotl32(x1, r); x1 ^= x0; }
    TF_R(13) TF_R(15) TF_R(26) TF_R(6)
    x0 += k1; x1 += k2 + 1u;
    TF_R(17) TF_R(29) TF_R(16) TF_R(24)
    x0 += k2; x1 += k0 + 2u;
    TF_R(13) TF_R(15) TF_R(26) TF_R(6)
    x0 += k0; x1 += k1 + 3u;
    TF_R(17) TF_R(29) TF_R(16) TF_R(24)
    x0 += k1; x1 += k2 + 4u;
    TF_R(13) TF_R(15) TF_R(26) TF_R(6)
    x0 += k2; x1 += k0 + 5u;
#undef TF_R
    o0 = x0; o1 = x1;
}

struct RKey { uint32_t a, b; };

__device__ __forceinline__ RKey kfold(RKey k, uint32_t i) {
    RKey r; threefry(k.a, k.b, 0u, i, r.a, r.b); return r;
}
__device__ __forceinline__ uint32_t kbits(RKey k) {
    uint32_t o0, o1; threefry(k.a, k.b, 0u, 0u, o0, o1); return o0 ^ o1;
}
__device__ __forceinline__ float u01(RKey k) {
    uint32_t b = (kbits(k) >> 9) | 0x3f800000u;
    return __uint_as_float(b) - 1.0f;
}
__device__ __forceinline__ float erfinv_xla(float x) {
    float xx = x * x;
    float w = -log1pf(-xx);
    float p;
    if (w < 5.0f) {
        float ww = w - 2.5f;
        p = 2.81022636e-08f;
        p = p * ww; p = p + 3.43273939e-07f;
        p = p * ww; p = p + -3.5233877e-06f;
        p = p * ww; p = p + -4.39150654e-06f;
        p = p * ww; p = p + 0.00021858087f;
        p = p * ww; p = p + -0.00125372503f;
        p = p * ww; p = p + -0.00417768164f;
        p = p * ww; p = p + 0.246640727f;
        p = p * ww; p = p + 1.50140941f;
    } else {
        float ww = sqrtf(w) - 3.0f;
        p = -0.000200214257f;
        p = p * ww; p = p + 0.000100950558f;
        p = p * ww; p = p + 0.00134934322f;
        p = p * ww; p = p + -0.00367342844f;
        p = p * ww; p = p + 0.00573950773f;
        p = p * ww; p = p + -0.0076224613f;
        p = p * ww; p = p + 0.00943887047f;
        p = p * ww; p = p + 1.00167406f;
        p = p * ww; p = p + 2.83297682f;
    }
    return p * x;
}
__device__ __forceinline__ float norm1(RKey k) {
    const float lo = -0.99999994f;
    float f = u01(k);
    float u = f * 2.0f;
    u = u + lo;
    u = fmaxf(lo, u);
    return 1.41421356f * erfinv_xla(u);
}

__device__ float gamma_log(RKey key, float alpha) {
    const float one_third = 0.33333334f;
    bool boost = (alpha >= 1.0f);
    float alpha_orig = alpha;
    if (!boost) alpha = alpha + 1.0f;
    float d = alpha - one_third;
    float c = one_third / sqrtf(d);

    RKey sub = kfold(key, 1u);
    key      = kfold(key, 0u);
    float log_boost = 0.0f;
    if (!boost) {
        float uB = u01(sub);
        log_boost = log1pf(-uB) * (1.0f / alpha_orig);
    }

    float X = 0.f, V = 1.f, U = 2.f;
    int guard = 0;
    do {
        RKey xk = kfold(key, 1u);
        RKey Uk = kfold(key, 2u);
        key     = kfold(key, 0u);
        float x = 0.f, v = -1.f;
        RKey kin = xk;
        int g2 = 0;
        do {
            RKey sk = kfold(kin, 1u);
            kin     = kfold(kin, 0u);
            x = norm1(sk);
            float cx = x * c;
            v = 1.0f + cx;
        } while (v <= 0.0f && ++g2 < 256);
        X = x * x;
        V = (v * v) * v;
        U = u01(Uk);
        float sq = 1.0f - 0.0331f * (X * X);
        if (U < sq) break;
        float bound = (X * 0.5f) + ((d - d * V) + d * logf(V));
        if (logf(U) < bound) break;
    } while (++guard < 256);

    float ls = logf(d) + logf(V);
    ls = ls + log_boost;
    return ls;
}

// ---------------------------------------------------------------------------
// Fused prologue: 3x f32->bf16 conversions + k_a (wave-local).
// blocks [0,8000): W_decoder cvt | [8000,8512): output cvt |
// [8512,11072): W_latent cvt    | [11072,11328): k_a, 4 tokens/block
// ---------------------------------------------------------------------------
__device__ __forceinline__ void cvt8(const float* __restrict__ src,
                                     unsigned short* __restrict__ dst, int i) {
    float4 v0 = *(const float4*)(src + i);
    float4 v1 = *(const float4*)(src + i + 4);
    us16x8 o;
    o[0] = f2b(v0.x); o[1] = f2b(v0.y); o[2] = f2b(v0.z); o[3] = f2b(v0.w);
    o[4] = f2b(v1.x); o[5] = f2b(v1.y); o[6] = f2b(v1.z); o[7] = f2b(v1.w);
    *(us16x8*)(dst + i) = o;
}

__global__ __launch_bounds__(256)
void k_pre(const float* __restrict__ Wdec, unsigned short* __restrict__ wdecb,
           const float* __restrict__ outp, unsigned short* __restrict__ outb,
           const float* __restrict__ Wlat, unsigned short* __restrict__ wlatb,
           const float* __restrict__ Wred, const float* __restrict__ bred,
           float* __restrict__ a_arr, float* __restrict__ dpar) {
    const int b = blockIdx.x, tid = threadIdx.x;
    if (b < 8000)  { cvt8(Wdec, wdecb, (b * 256 + tid) * 8); return; }
    if (b < 8512)  { cvt8(outp, outb, ((b - 8000) * 256 + tid) * 8); return; }
    if (b < 11072) { cvt8(Wlat, wlatb, ((b - 8512) * 256 + tid) * 8); return; }
    // k_a, wave-local (butterfly leaves full sum on all lanes; no LDS needed)
    const int n = (b - 11072) * 4 + (tid >> 6);
    const int lane = tid & 63;
    const float* orow = outp + (size_t)n * NHID;
    float z[NEXP];
    for (int e = 0; e < NEXP; ++e) {
        const float* wrow = Wred + (size_t)e * NHID;
        float s = 0.f;
        for (int k = lane; k < NHID; k += 64) s += orow[k] * wrow[k];
        for (int off = 32; off; off >>= 1) s += __shfl_xor(s, off);
        z[e] = s + bred[e];
    }
    if (lane == 0) {
        float a[NEXP];
        float bb = 0.f;
        for (int e = 0; e < NEXP; ++e)
            a[e] = fmaxf(z[e], 0.f) + log1pf(expf(-fabsf(z[e]))) + 1e-8f;
        for (int e = 0; e < NEXP; ++e) bb += a[e];
        float cs = 0.f;
        for (int e = 0; e < NEXP; ++e) {
            cs += a[e];
            float dd = fmaxf(fabsf(bb - cs), 1e-8f);
            a_arr[n * NEXP + e] = a[e];
            dpar [n * NEXP + e] = dd;
        }
    }
}

// ---------------------------------------------------------------------------
// k_pis: fallback path only
// ---------------------------------------------------------------------------
__global__ void k_pis(const float* __restrict__ sample, float* __restrict__ pis) {
    int n = blockIdx.x * blockDim.x + threadIdx.x;
    if (n >= NROW) return;
    float rp = 1.0f;
    for (int e = 0; e < NEXP; ++e) {
        float s = sample[n * NEXP + e];
        pis[n * NEXP + e] = rp * s;
        rp = rp * (1.0f - s);
    }
}

// w = pis / Z on rows [r0, r0+cnt)   (fallback path only)
__global__ void k_w(const float* __restrict__ pis, const float* __restrict__ Z,
                    float* __restrict__ w, int r0, int cnt) {
    int i = blockIdx.x * 256 + threadIdx.x;
    if (i >= cnt) return;
    int r = r0 + i;
    w[r] = pis[r] / Z[r];
}

// ---------------------------------------------------------------------------
// Combine span: out[n0+nl, c] = sum_e (stickbreak(sample)/Z) * P[nl*10+e, c]
// pis computed inline from sample (identical arithmetic to k_pis + divide).
// P read + out write non-temporal (keep L3 for B).
// ---------------------------------------------------------------------------
__device__ __forceinline__ void combine_span(const unsigned short* __restrict__ P,
                                             const float* __restrict__ sample,
                                             const float* __restrict__ Z,
                                             float* __restrict__ out,
                                             int n0, int items, int idx0, int stride) {
    for (int idx = idx0; idx < items; idx += stride) {
        int nl = idx / 4000;
        int c8 = (idx - nl * 4000) * 8;
        int n  = n0 + nl;
        const float* sr = sample + n * NEXP;
        const float* Zr = Z + n * NEXP;
        float w[NEXP];
        float rp = 1.0f;
#pragma unroll
        for (int e = 0; e < NEXP; ++e) {
            float sv = sr[e];
            float pv = rp * sv;
            w[e] = pv / Zr[e];
            rp = rp * (1.0f - sv);
        }
        float s[8] = {0.f,0.f,0.f,0.f,0.f,0.f,0.f,0.f};
        const unsigned short* Pr = P + (size_t)nl * NEXP * NTOK + c8;
#pragma unroll
        for (int e = 0; e < NEXP; ++e) {
            us16x8 v = __builtin_nontemporal_load((const us16x8*)(Pr + (size_t)e * NTOK));
#pragma unroll
            for (int jj = 0; jj < 8; ++jj)
                s[jj] = s[jj] + w[e] * b2f(v[jj]);
        }
        float* orow = out + (size_t)n * NTOK + c8;
        f32x4 o0 = {s[0], s[1], s[2], s[3]};
        f32x4 o1 = {s[4], s[5], s[6], s[7]};
        __builtin_nontemporal_store(o0, (f32x4*)(orow));
        __builtin_nontemporal_store(o1, (f32x4*)(orow + 4));
    }
}

__global__ __launch_bounds__(256)
void k_fin(const unsigned short* __restrict__ P,
           const float* __restrict__ sample,
           const float* __restrict__ Z,
           float* __restrict__ out, int n0, int items) {
    combine_span(P, sample, Z, out, n0, items,
                 (int)(blockIdx.x * 256u + threadIdx.x),
                 (int)(gridDim.x * 256u));
}

// ---------------------------------------------------------------------------
// Fused mid: k_latm (blocks 0..319) + k_sample (blocks 320..359).
// latm: latb = bf16(tanh(outb · wlatb^T + b_latent)), XCD stripe, prefetch dbuf
// ---------------------------------------------------------------------------
__global__ __launch_bounds__(256)
void k_mid(const unsigned short* __restrict__ A,
           const unsigned short* __restrict__ B,
           const float* __restrict__ bias,
           unsigned short* __restrict__ dst,
           const float* __restrict__ a_arr,
           const float* __restrict__ dpar,
           float* __restrict__ sample) {
    if (blockIdx.x >= 320) {
        // k_sample body
        int i = ((int)blockIdx.x - 320) * 256 + (int)threadIdx.x;
        if (i >= MROWS) return;
        RKey root{0u, 42u};
        RKey ka = kfold(root, 0u);
        RKey kb = kfold(root, 1u);
        float lga = gamma_log(kfold(ka, (uint32_t)i), a_arr[i]);
        float lgb = gamma_log(kfold(kb, (uint32_t)i), dpar[i]);
        float lm = fmaxf(lga, lgb);
        float ea = expf(lga - lm), eb = expf(lgb - lm);
        sample[i] = ea / (ea + eb);
        return;
    }
    __shared__ unsigned short Als[2][128 * 64];   // 2 x 16 KB
    __shared__ unsigned short Bls[2][128 * 64];   // 2 x 16 KB
    const int tid  = threadIdx.x;
    const int lane = tid & 63, wid = tid >> 6;
    const int wm = wid >> 1, wn = wid & 1;
    const uint32_t l = blockIdx.x;             // 320 = 8 xcd * 40 cols
    const int row0 = (int)(l & 7u) * 128;      // row-stripe per XCD
    const int col0 = (int)(l >> 3) * 128;
    const int lrow8 = lane >> 3, lslot = lane & 7;

    const unsigned short* pA[4];
    const unsigned short* pB[4];
#pragma unroll
    for (int i = 0; i < 4; ++i) {
        int rA = wid * 32 + i * 8 + lrow8;
        pA[i] = A + (size_t)(row0 + rA) * NHID + ((lslot ^ (rA & 7)) << 3);
        int rB = wid * 32 + i * 8 + lrow8;
        pB[i] = B + (size_t)(col0 + rB) * NHID + ((lslot ^ (rB & 7)) << 3);
    }
    int offA[2][4], offB[2][4];
#pragma unroll
    for (int kh = 0; kh < 2; ++kh)
#pragma unroll
        for (int f = 0; f < 4; ++f) {
            int rA = wm * 64 + f * 16 + (lane & 15);
            offA[kh][f] = rA * 128 + ((((lane >> 4) * 16) + kh * 64) ^ ((rA & 7) << 4));
            int rB = wn * 64 + f * 16 + (lane & 15);
            offB[kh][f] = rB * 128 + ((((lane >> 4) * 16) + kh * 64) ^ ((rB & 7) << 4));
        }

    f32x4 acc[4][4];
#pragma unroll
    for (int mf = 0; mf < 4; ++mf)
#pragma unroll
        for (int nf = 0; nf < 4; ++nf) acc[mf][nf] = (f32x4)0.f;

#pragma unroll
    for (int i = 0; i < 4; ++i) {
        GLD16(pA[i], (char*)&Als[0][0] + (wid * 32 + i * 8) * 128); pA[i] += 64;
        GLD16(pB[i], (char*)&Bls[0][0] + (wid * 32 + i * 8) * 128); pB[i] += 64;
    }
    __syncthreads();

#pragma unroll
    for (int t = 0; t < 16; ++t) {
        const int cur = t & 1, nxt = cur ^ 1;
        if (t < 15) {
#pragma unroll
            for (int i = 0; i < 4; ++i) {
                GLD16(pA[i], (char*)&Als[nxt][0] + (wid * 32 + i * 8) * 128); pA[i] += 64;
                GLD16(pB[i], (char*)&Bls[nxt][0] + (wid * 32 + i * 8) * 128); pB[i] += 64;
            }
        }
        const char* Ab = (const char*)&Als[cur][0];
        const char* Bb = (const char*)&Bls[cur][0];
#pragma unroll
        for (int kh = 0; kh < 2; ++kh) {
            bf16x8 af[4], bfr[4];
#pragma unroll
            for (int f = 0; f < 4; ++f) {
                af[f]  = *(const bf16x8*)(Ab + offA[kh][f]);
                bfr[f] = *(const bf16x8*)(Bb + offB[kh][f]);
            }
#pragma unroll
            for (int mf = 0; mf < 4; ++mf)
#pragma unroll
                for (int nf = 0; nf < 4; ++nf)
                    acc[mf][nf] = __builtin_amdgcn_mfma_f32_16x16x32_bf16(
                        af[mf], bfr[nf], acc[mf][nf], 0, 0, 0);
        }
        __syncthreads();               // per-wave vmcnt(0): prefetch landed
    }

    const int q = lane >> 4, cl = lane & 15;
#pragma unroll
    for (int mf = 0; mf < 4; ++mf) {
#pragma unroll
        for (int nf = 0; nf < 4; ++nf) {
            int col = col0 + wn * 64 + nf * 16 + cl;
            float bc = bias[col];
#pragma unroll
            for (int j = 0; j < 4; ++j) {
                int r = row0 + wm * 64 + mf * 16 + q * 4 + j;
                dst[(size_t)r * NLAT + col] = f2b(tanhf(acc[mf][nf][j] + bc));
            }
        }
    }
}

// ---------------------------------------------------------------------------
// MFMA decoder pass: prefetch dbuf (verified round-15 structure) + XCD stripe
// + hoisted addressing. tile 160x128, BK=64, 4 waves, 5x4 frags 16x16x32.
// MODE 1: Z only  MODE 2: out=w*exp (fallback)
// MODE 3: Z + P-chunk via LDS-staged coalesced nt-stores (stride 272 B)
// MODE 3 fused: blocks >= nGemm run combine_span for the PREVIOUS chunk.
// ---------------------------------------------------------------------------
template<int MODE>
__global__ __launch_bounds__(256)
void k_dec(const unsigned short* __restrict__ A,
           const unsigned short* __restrict__ B,
           const float* __restrict__ bias,
           const float* __restrict__ wmix,
           float* __restrict__ dst,
           unsigned short* __restrict__ Pst,
           int rb0, int nRB, int nGemm,
           const float* __restrict__ sample,
           const float* __restrict__ Zarr,
           float* __restrict__ outp,
           const unsigned short* __restrict__ Pprev,
           int n0prev, int itemsPrev) {
    if (MODE == 3 && (int)blockIdx.x >= nGemm) {
        const int cb = (int)blockIdx.x - nGemm;
        combine_span(Pprev, sample, Zarr, outp, n0prev, itemsPrev,
                     cb * 256 + (int)threadIdx.x,
                     ((int)gridDim.x - nGemm) * 256);
        return;
    }
    // unified LDS arena: [0,40960) = Als[2], [40960,73728) = Bls[2];
    // epilogue reuses [0, 160*272) as P staging (row stride 272 B, 16B-aligned)
    __shared__ __align__(16) unsigned char lds_raw[73728];
    unsigned short (*Als)[160 * 64] = (unsigned short (*)[160 * 64])lds_raw;
    unsigned short (*Bls)[128 * 64] = (unsigned short (*)[128 * 64])(lds_raw + 40960);
    const int tid  = threadIdx.x;
    const int lane = tid & 63, wid = tid >> 6;
    const int wm = wid >> 1, wn = wid & 1;
    const uint32_t l = blockIdx.x;
    int by_l, bx;
    if (nRB >= 8 && (nRB & 7) == 0) {  // XCD stripe: xcd = l%8 owns nRB/8 rows
        const int per = nRB >> 3;
        const uint32_t jb = l >> 3;
        by_l = (int)(l & 7u) * per + (int)(jb % (uint32_t)per);
        bx   = (int)(jb / (uint32_t)per);
    } else {
        by_l = (int)(l % (uint32_t)nRB);
        bx   = (int)(l / (uint32_t)nRB);
    }
    const int by   = rb0 + by_l;
    const int row0 = by * 160;
    const int rl0  = by_l * 160;       // P-local row base
    const int col0 = bx * 128;
    const int lrow8 = lane >> 3, lslot = lane & 7;

    const unsigned short* pA[5];
    const unsigned short* pB[4];
#pragma unroll
    for (int i = 0; i < 5; ++i) {
        int rA = wid * 40 + i * 8 + lrow8;
        pA[i] = A + (size_t)(row0 + rA) * 512 + ((lslot ^ (rA & 7)) << 3);
    }
#pragma unroll
    for (int i = 0; i < 4; ++i) {
        int rB = wid * 32 + i * 8 + lrow8;
        pB[i] = B + (size_t)(col0 + rB) * 512 + ((lslot ^ (rB & 7)) << 3);
    }
    int offA[2][5], offB[2][4];
#pragma unroll
    for (int kh = 0; kh < 2; ++kh) {
#pragma unroll
        for (int mf = 0; mf < 5; ++mf) {
            int r = wm * 80 + mf * 16 + (lane & 15);
            offA[kh][mf] = r * 128 + ((((lane >> 4) * 16) + kh * 64) ^ ((r & 7) << 4));
        }
#pragma unroll
        for (int nf = 0; nf < 4; ++nf) {
            int r = wn * 64 + nf * 16 + (lane & 15);
            offB[kh][nf] = r * 128 + ((((lane >> 4) * 16) + kh * 64) ^ ((r & 7) << 4));
        }
    }

    f32x4 acc[5][4];
#pragma unroll
    for (int mf = 0; mf < 5; ++mf)
#pragma unroll
        for (int nf = 0; nf < 4; ++nf) acc[mf][nf] = (f32x4)0.f;

    // prologue: tile 0 -> buf 0
#pragma unroll
    for (int i = 0; i < 5; ++i) {
        GLD16(pA[i], (char*)&Als[0][0] + (wid * 40 + i * 8) * 128); pA[i] += 64;
    }
#pragma unroll
    for (int i = 0; i < 4; ++i) {
        GLD16(pB[i], (char*)&Bls[0][0] + (wid * 32 + i * 8) * 128); pB[i] += 64;
    }
    __syncthreads();

#pragma unroll
    for (int t = 0; t < 8; ++t) {
        const int cur = t & 1, nxt = cur ^ 1;
        if (t < 7) {
#pragma unroll
            for (int i = 0; i < 5; ++i) {
                GLD16(pA[i], (char*)&Als[nxt][0] + (wid * 40 + i * 8) * 128); pA[i] += 64;
            }
#pragma unroll
            for (int i = 0; i < 4; ++i) {
                GLD16(pB[i], (char*)&Bls[nxt][0] + (wid * 32 + i * 8) * 128); pB[i] += 64;
            }
        }
        const char* Ab = (const char*)&Als[cur][0];
        const char* Bb = (const char*)&Bls[cur][0];
#pragma unroll
        for (int kh = 0; kh < 2; ++kh) {
            bf16x8 af[5], bfr[4];
#pragma unroll
            for (int mf = 0; mf < 5; ++mf)
                af[mf] = *(const bf16x8*)(Ab + offA[kh][mf]);
#pragma unroll
            for (int nf = 0; nf < 4; ++nf)
                bfr[nf] = *(const bf16x8*)(Bb + offB[kh][nf]);
#pragma unroll
            for (int mf = 0; mf < 5; ++mf)
#pragma unroll
                for (int nf = 0; nf < 4; ++nf)
                    acc[mf][nf] = __builtin_amdgcn_mfma_f32_16x16x32_bf16(
                        af[mf], bfr[nf], acc[mf][nf], 0, 0, 0);
        }
        __syncthreads();               // per-wave vmcnt(0): prefetch landed
    }

    // C layout per frag: row = (lane>>4)*4 + j, col = lane&15  [m89-verified]
    const int q = lane >> 4, cl = lane & 15;
    float bv[4];
#pragma unroll
    for (int nf = 0; nf < 4; ++nf) bv[nf] = bias[col0 + wn * 64 + nf * 16 + cl];

    if (MODE == 3) {
        // exp + Z atomics + stage P tile into LDS (row stride 272 B)
#pragma unroll
        for (int mf = 0; mf < 5; ++mf) {
#pragma unroll
            for (int jj = 0; jj < 4; ++jj) {
                const int rr = wm * 80 + mf * 16 + q * 4 + jj;
                float p0 = expf(acc[mf][0][jj] + bv[0]);
                float p1 = expf(acc[mf][1][jj] + bv[1]);
                float p2 = expf(acc[mf][2][jj] + bv[2]);
                float p3 = expf(acc[mf][3][jj] + bv[3]);
                float s = ((p0 + p1) + (p2 + p3));
                s += __shfl_xor(s, 1); s += __shfl_xor(s, 2);
                s += __shfl_xor(s, 4); s += __shfl_xor(s, 8);
                if (cl == 0) atomicAdd(&dst[row0 + rr], s);
                unsigned short* lrow = (unsigned short*)(lds_raw + rr * 272);
                lrow[wn * 64 + cl]      = f2b(p0);
                lrow[wn * 64 + 16 + cl] = f2b(p1);
                lrow[wn * 64 + 32 + cl] = f2b(p2);
                lrow[wn * 64 + 48 + cl] = f2b(p3);
            }
        }
        __syncthreads();
        // coalesced writeout: 256 threads = 16 rows x 16 lanes, 10 passes
        const int rloc = tid >> 4, c16 = tid & 15;
#pragma unroll
        for (int it = 0; it < 10; ++it) {
            int gr = it * 16 + rloc;
            us16x8 v = *(const us16x8*)(lds_raw + gr * 272 + c16 * 16);
            __builtin_nontemporal_store(
                v, (us16x8*)(Pst + (size_t)(rl0 + gr) * NTOK + col0 + c16 * 8));
        }
    } else if (MODE == 1) {
#pragma unroll
        for (int mf = 0; mf < 5; ++mf) {
#pragma unroll
            for (int jj = 0; jj < 4; ++jj) {
                const int rr = wm * 80 + mf * 16 + q * 4 + jj;
                float p0 = expf(acc[mf][0][jj] + bv[0]);
                float p1 = expf(acc[mf][1][jj] + bv[1]);
                float p2 = expf(acc[mf][2][jj] + bv[2]);
                float p3 = expf(acc[mf][3][jj] + bv[3]);
                float s = ((p0 + p1) + (p2 + p3));
                s += __shfl_xor(s, 1); s += __shfl_xor(s, 2);
                s += __shfl_xor(s, 4); s += __shfl_xor(s, 8);
                if (cl == 0) atomicAdd(&dst[row0 + rr], s);
            }
        }
    } else {
        float wv[5][4];
#pragma unroll
        for (int mf = 0; mf < 5; ++mf)
#pragma unroll
            for (int jj = 0; jj < 4; ++jj)
                wv[mf][jj] = wmix[row0 + wm * 80 + mf * 16 + q * 4 + jj];
#pragma unroll
        for (int mf = 0; mf < 5; ++mf)
#pragma unroll
            for (int nf = 0; nf < 4; ++nf)
#pragma unroll
                for (int jj = 0; jj < 4; ++jj)
                    acc[mf][nf][jj] = wv[mf][jj] * expf(acc[mf][nf][jj] + bv[nf]);

        const int tok0 = by * 16 + wm * 8;
#pragma unroll
        for (int t = 0; t < 8; ++t) {
#pragma unroll
            for (int nf = 0; nf < 4; ++nf) {
                float s = 0.f;
#pragma unroll
                for (int i = 0; i < 10; ++i) {
                    const int rl = 10 * t + i;
                    const int mf = rl >> 4, qr = (rl >> 2) & 3, jj = rl & 3;
                    s += (q == qr) ? acc[mf][nf][jj] : 0.f;
                }
                s += __shfl_xor(s, 16);
                s += __shfl_xor(s, 32);
                if (q == 0)
                    dst[(size_t)(tok0 + t) * NTOK + col0 + wn * 64 + nf * 16 + cl] = s;
            }
        }
    }
}

// ---------------------------------------------------------------------------
extern "C" void kernel_launch(void* const* d_in, const int* in_sizes, int n_in,
                              void* d_out, int out_size, void* d_ws, size_t ws_size,
                              hipStream_t stream) {
    const float* output    = (const float*)d_in[0];  // [1024,1024]
    const float* W_latent  = (const float*)d_in[1];  // [5120,1024]
    const float* b_latent  = (const float*)d_in[2];  // [5120]
    const float* W_decoder = (const float*)d_in[3];  // [32000,512]
    const float* b_decoder = (const float*)d_in[4];  // [32000]
    const float* W_reduce  = (const float*)d_in[5];  // [10,1024]
    const float* b_reduce  = (const float*)d_in[6];  // [10]
    float* out = (float*)d_out;                      // [1024,32000]

    // ws layout: latb(10.49MB) | wdecb(32.77MB) | 6x f32[MROWS] | P buffers
    char* wsb = (char*)d_ws;
    unsigned short* latb  = (unsigned short*)wsb;
    unsigned short* wdecb = (unsigned short*)(wsb + 10485760);
    float* a_arr  = (float*)(wsb + 10485760 + 32768000);
    float* dpar   = a_arr  + MROWS;
    float* sample = dpar   + MROWS;
    float* pis    = sample + MROWS;
    float* Z      = pis    + MROWS;
    float* wmix   = Z      + MROWS;
    unsigned short* Pbuf = (unsigned short*)(wmix + MROWS);
    const size_t BASE = 10485760ull + 32768000ull + 6ull * MROWS * 4ull;
    const size_t avail = (ws_size > BASE) ? (ws_size - BASE) : 0;

    // choose: double-buffered chunk (fused combine) > single chunk > fallback
    int CRd = 0, CRs = 0;
    {
        const int cands[4] = {2560, 1280, 640, 320};
        for (int c = 0; c < 4; ++c)
            if (2ull * (size_t)cands[c] * NTOK * 2ull <= avail) { CRd = cands[c]; break; }
        if (CRd == 0) {
            const int cs[5] = {2560, 1280, 640, 320, 160};
            for (int c = 0; c < 5; ++c)
                if ((size_t)cs[c] * NTOK * 2ull <= avail) { CRs = cs[c]; break; }
        }
    }

    // bf16 copies of output/W_latent live in d_out (fully overwritten later)
    unsigned short* outb  = (unsigned short*)d_out;
    unsigned short* wlatb = (unsigned short*)((char*)d_out + 2097152);

    // fused prologue: 3 conversions + k_a
    k_pre<<<11328, 256, 0, stream>>>(W_decoder, wdecb, output, outb,
                                     W_latent, wlatb, W_reduce, b_reduce,
                                     a_arr, dpar);
    // fused mid: latent GEMM + beta sampling
    k_mid<<<360, 256, 0, stream>>>(outb, wlatb, b_latent, latb,
                                   a_arr, dpar, sample);

    (void)hipMemsetAsync(Z, 0, MROWS * sizeof(float), stream);

    if (CRd > 0) {
        // fused path: GEMM(ci) + combine(ci-1) in one launch, double Pbuf.
        const int nRB = CRd / 160, nGemm = nRB * 250, nch = MROWS / CRd;
        const int items = (CRd / 10) * 4000;
        for (int ci = 0; ci < nch; ++ci) {
            unsigned short* Pcur  = Pbuf + (size_t)(ci & 1) * CRd * NTOK;
            unsigned short* Pprev = Pbuf + (size_t)((ci & 1) ^ 1) * CRd * NTOK;
            const int extra = (ci > 0) ? 1000 : 0;
            k_dec<3><<<nGemm + extra, 256, 0, stream>>>(
                latb, wdecb, b_decoder, nullptr, Z, Pcur, ci * nRB, nRB, nGemm,
                sample, Z, out, Pprev, (ci - 1) * (CRd / 10), items);
        }
        unsigned short* Plast = Pbuf + (size_t)((nch - 1) & 1) * CRd * NTOK;
        k_fin<<<items / 256, 256, 0, stream>>>(Plast, sample, Z, out,
                                               (nch - 1) * (CRd / 10), items);
    } else if (CRs > 0) {
        // single-buffer chunked path
        const int nRB = CRs / 160;
        const int items = (CRs / 10) * 4000;
        for (int r0 = 0; r0 < MROWS; r0 += CRs) {
            k_dec<3><<<nRB * 250, 256, 0, stream>>>(
                latb, wdecb, b_decoder, nullptr, Z, Pbuf, r0 / 160, nRB, 1 << 30,
                sample, Z, out, nullptr, 0, 0);
            k_fin<<<items / 256, 256, 0, stream>>>(Pbuf, sample, Z, out,
                                                   r0 / 10, items);
        }
    } else {
        // fallback: two full GEMM passes
        k_pis<<<(NROW + 255) / 256, 256, 0, stream>>>(sample, pis);
        k_dec<1><<<16000, 256, 0, stream>>>(latb, wdecb, b_decoder, nullptr, Z,
                                            nullptr, 0, 64, 1 << 30,
                                            sample, Z, out, nullptr, 0, 0);
        k_w<<<MROWS / 256, 256, 0, stream>>>(pis, Z, wmix, 0, MROWS);
        k_dec<2><<<16000, 256, 0, stream>>>(latb, wdecb, b_decoder, wmix, out,
                                            nullptr, 0, 64, 1 << 30,
                                            sample, Z, out, nullptr, 0, 0);
    }
    (void)in_sizes; (void)n_in; (void)out_size;
}

// Round 21
// 800.295 us; speedup vs baseline: 1.4029x; 1.0006x over previous
//
#include <hip/hip_runtime.h>
#include <cstdint>
#include <cstddef>

#pragma clang fp contract(off)

#define NTOK  32000
#define NINP  512
#define NHID  1024
#define NEXP  10
#define NROW  1024            // N (tokens)
#define NLAT  (NEXP*NINP)     // 5120
#define MROWS (NROW*NEXP)     // 10240

typedef __attribute__((ext_vector_type(4))) float f32x4;
typedef __attribute__((ext_vector_type(8))) short bf16x8;
typedef __attribute__((ext_vector_type(8))) unsigned short us16x8;

// async global->LDS, 16B per lane: LDS dest = wave-uniform base + lane*16
#define GLD16(g, l) __builtin_amdgcn_global_load_lds(                       \
    (const __attribute__((address_space(1))) void*)(g),                     \
    (__attribute__((address_space(3))) void*)(l), 16, 0, 0)

// f32 -> bf16 round-to-nearest-even
__device__ __forceinline__ unsigned short f2b(float x) {
    uint32_t u = __float_as_uint(x);
    uint32_t r = (u + 0x7fffu + ((u >> 16) & 1u)) >> 16;
    return (unsigned short)r;
}
__device__ __forceinline__ float b2f(unsigned short b) {
    return __uint_as_float(((uint32_t)b) << 16);
}

// ---------------------------------------------------------------------------
// threefry2x32 (JAX-exact)
// ---------------------------------------------------------------------------
__device__ __forceinline__ uint32_t rotl32(uint32_t v, int r) {
    return (v << r) | (v >> (32 - r));
}

__device__ __forceinline__ void threefry(uint32_t k0, uint32_t k1,
                                         uint32_t x0, uint32_t x1,
                                         uint32_t& o0, uint32_t& o1) {
    uint32_t k2 = k0 ^ k1 ^ 0x1BD11BDAu;
    x0 += k0; x1 += k1;
#define TF_R(r) { x0 += x1; x1 = rotl32(x1, r); x1 ^= x0; }
    TF_R(13) TF_R(15) TF_R(26) TF_R(6)
    x0 += k1; x1 += k2 + 1u;
    TF_R(17) TF_R(29) TF_R(16) TF_R(24)
    x0 += k2; x1 += k0 + 2u;
    TF_R(13) TF_R(15) TF_R(26) TF_R(6)
    x0 += k0; x1 += k1 + 3u;
    TF_R(17) TF_R(29) TF_R(16) TF_R(24)
    x0 += k1; x1 += k2 + 4u;
    TF_R(13) TF_R(15) TF_R(26) TF_R(6)
    x0 += k2; x1 += k0 + 5u;
#undef TF_R
    o0 = x0; o1 = x1;
}

struct RKey { uint32_t a, b; };

__device__ __forceinline__ RKey kfold(RKey k, uint32_t i) {
    RKey r; threefry(k.a, k.b, 0u, i, r.a, r.b); return r;
}
__device__ __forceinline__ uint32_t kbits(RKey k) {
    uint32_t o0, o1; threefry(k.a, k.b, 0u, 0u, o0, o1); return o0 ^ o1;
}
__device__ __forceinline__ float u01(RKey k) {
    uint32_t b = (kbits(k) >> 9) | 0x3f800000u;
    return __uint_as_float(b) - 1.0f;
}
__device__ __forceinline__ float erfinv_xla(float x) {
    float xx = x * x;
    float w = -log1pf(-xx);
    float p;
    if (w < 5.0f) {
        float ww = w - 2.5f;
        p = 2.81022636e-08f;
        p = p * ww; p = p + 3.43273939e-07f;
        p = p * ww; p = p + -3.5233877e-06f;
        p = p * ww; p = p + -4.39150654e-06f;
        p = p * ww; p = p + 0.00021858087f;
        p = p * ww; p = p + -0.00125372503f;
        p = p * ww; p = p + -0.00417768164f;
        p = p * ww; p = p + 0.246640727f;
        p = p * ww; p = p + 1.50140941f;
    } else {
        float ww = sqrtf(w) - 3.0f;
        p = -0.000200214257f;
        p = p * ww; p = p + 0.000100950558f;
        p = p * ww; p = p + 0.00134934322f;
        p = p * ww; p = p + -0.00367342844f;
        p = p * ww; p = p + 0.00573950773f;
        p = p * ww; p = p + -0.0076224613f;
        p = p * ww; p = p + 0.00943887047f;
        p = p * ww; p = p + 1.00167406f;
        p = p * ww; p = p + 2.83297682f;
    }
    return p * x;
}
__device__ __forceinline__ float norm1(RKey k) {
    const float lo = -0.99999994f;
    float f = u01(k);
    float u = f * 2.0f;
    u = u + lo;
    u = fmaxf(lo, u);
    return 1.41421356f * erfinv_xla(u);
}

__device__ float gamma_log(RKey key, float alpha) {
    const float one_third = 0.33333334f;
    bool boost = (alpha >= 1.0f);
    float alpha_orig = alpha;
    if (!boost) alpha = alpha + 1.0f;
    float d = alpha - one_third;
    float c = one_third / sqrtf(d);

    RKey sub = kfold(key, 1u);
    key      = kfold(key, 0u);
    float log_boost = 0.0f;
    if (!boost) {
        float uB = u01(sub);
        log_boost = log1pf(-uB) * (1.0f / alpha_orig);
    }

    float X = 0.f, V = 1.f, U = 2.f;
    int guard = 0;
    do {
        RKey xk = kfold(key, 1u);
        RKey Uk = kfold(key, 2u);
        key     = kfold(key, 0u);
        float x = 0.f, v = -1.f;
        RKey kin = xk;
        int g2 = 0;
        do {
            RKey sk = kfold(kin, 1u);
            kin     = kfold(kin, 0u);
            x = norm1(sk);
            float cx = x * c;
            v = 1.0f + cx;
        } while (v <= 0.0f && ++g2 < 256);
        X = x * x;
        V = (v * v) * v;
        U = u01(Uk);
        float sq = 1.0f - 0.0331f * (X * X);
        if (U < sq) break;
        float bound = (X * 0.5f) + ((d - d * V) + d * logf(V));
        if (logf(U) < bound) break;
    } while (++guard < 256);

    float ls = logf(d) + logf(V);
    ls = ls + log_boost;
    return ls;
}

// ---------------------------------------------------------------------------
// Fused prologue: 3x f32->bf16 conversions + k_a (wave-local) + Z zeroing.
// blocks [0,8000): W_decoder cvt | [8000,8512): output cvt |
// [8512,11072): W_latent cvt | [11072,11328): k_a | [11328,11338): Z = 0
// ---------------------------------------------------------------------------
__device__ __forceinline__ void cvt8(const float* __restrict__ src,
                                     unsigned short* __restrict__ dst, int i) {
    float4 v0 = *(const float4*)(src + i);
    float4 v1 = *(const float4*)(src + i + 4);
    us16x8 o;
    o[0] = f2b(v0.x); o[1] = f2b(v0.y); o[2] = f2b(v0.z); o[3] = f2b(v0.w);
    o[4] = f2b(v1.x); o[5] = f2b(v1.y); o[6] = f2b(v1.z); o[7] = f2b(v1.w);
    *(us16x8*)(dst + i) = o;
}

__global__ __launch_bounds__(256)
void k_pre(const float* __restrict__ Wdec, unsigned short* __restrict__ wdecb,
           const float* __restrict__ outp, unsigned short* __restrict__ outb,
           const float* __restrict__ Wlat, unsigned short* __restrict__ wlatb,
           const float* __restrict__ Wred, const float* __restrict__ bred,
           float* __restrict__ a_arr, float* __restrict__ dpar,
           float* __restrict__ Z) {
    const int b = blockIdx.x, tid = threadIdx.x;
    if (b < 8000)  { cvt8(Wdec, wdecb, (b * 256 + tid) * 8); return; }
    if (b < 8512)  { cvt8(outp, outb, ((b - 8000) * 256 + tid) * 8); return; }
    if (b < 11072) { cvt8(Wlat, wlatb, ((b - 8512) * 256 + tid) * 8); return; }
    if (b < 11328) {
        // k_a, wave-local (butterfly leaves full sum on all lanes)
        const int n = (b - 11072) * 4 + (tid >> 6);
        const int lane = tid & 63;
        const float* orow = outp + (size_t)n * NHID;
        float z[NEXP];
        for (int e = 0; e < NEXP; ++e) {
            const float* wrow = Wred + (size_t)e * NHID;
            float s = 0.f;
            for (int k = lane; k < NHID; k += 64) s += orow[k] * wrow[k];
            for (int off = 32; off; off >>= 1) s += __shfl_xor(s, off);
            z[e] = s + bred[e];
        }
        if (lane == 0) {
            float a[NEXP];
            float bb = 0.f;
            for (int e = 0; e < NEXP; ++e)
                a[e] = fmaxf(z[e], 0.f) + log1pf(expf(-fabsf(z[e]))) + 1e-8f;
            for (int e = 0; e < NEXP; ++e) bb += a[e];
            float cs = 0.f;
            for (int e = 0; e < NEXP; ++e) {
                cs += a[e];
                float dd = fmaxf(fabsf(bb - cs), 1e-8f);
                a_arr[n * NEXP + e] = a[e];
                dpar [n * NEXP + e] = dd;
            }
        }
        return;
    }
    // Z zeroing: 10 blocks x 256 threads x 4 floats = 10240 = MROWS
    const int i = ((b - 11328) * 256 + tid) * 4;
    f32x4 zz = (f32x4)0.f;
    *(f32x4*)(Z + i) = zz;
}

// ---------------------------------------------------------------------------
// k_pis / k_w: fallback path only
// ---------------------------------------------------------------------------
__global__ void k_pis(const float* __restrict__ sample, float* __restrict__ pis) {
    int n = blockIdx.x * blockDim.x + threadIdx.x;
    if (n >= NROW) return;
    float rp = 1.0f;
    for (int e = 0; e < NEXP; ++e) {
        float s = sample[n * NEXP + e];
        pis[n * NEXP + e] = rp * s;
        rp = rp * (1.0f - s);
    }
}

__global__ void k_w(const float* __restrict__ pis, const float* __restrict__ Z,
                    float* __restrict__ w, int r0, int cnt) {
    int i = blockIdx.x * 256 + threadIdx.x;
    if (i >= cnt) return;
    int r = r0 + i;
    w[r] = pis[r] / Z[r];
}

// ---------------------------------------------------------------------------
// Combine span: out[n0+nl, c] = sum_e (stickbreak(sample)/Z) * P[nl*10+e, c]
// pis computed inline from sample (identical arithmetic to k_pis + divide).
// P read + out write non-temporal (keep L3 for B).
// ---------------------------------------------------------------------------
__device__ __forceinline__ void combine_span(const unsigned short* __restrict__ P,
                                             const float* __restrict__ sample,
                                             const float* __restrict__ Z,
                                             float* __restrict__ out,
                                             int n0, int items, int idx0, int stride) {
    for (int idx = idx0; idx < items; idx += stride) {
        int nl = idx / 4000;
        int c8 = (idx - nl * 4000) * 8;
        int n  = n0 + nl;
        const float* sr = sample + n * NEXP;
        const float* Zr = Z + n * NEXP;
        float w[NEXP];
        float rp = 1.0f;
#pragma unroll
        for (int e = 0; e < NEXP; ++e) {
            float sv = sr[e];
            float pv = rp * sv;
            w[e] = pv / Zr[e];
            rp = rp * (1.0f - sv);
        }
        float s[8] = {0.f,0.f,0.f,0.f,0.f,0.f,0.f,0.f};
        const unsigned short* Pr = P + (size_t)nl * NEXP * NTOK + c8;
#pragma unroll
        for (int e = 0; e < NEXP; ++e) {
            us16x8 v = __builtin_nontemporal_load((const us16x8*)(Pr + (size_t)e * NTOK));
#pragma unroll
            for (int jj = 0; jj < 8; ++jj)
                s[jj] = s[jj] + w[e] * b2f(v[jj]);
        }
        float* orow = out + (size_t)n * NTOK + c8;
        f32x4 o0 = {s[0], s[1], s[2], s[3]};
        f32x4 o1 = {s[4], s[5], s[6], s[7]};
        __builtin_nontemporal_store(o0, (f32x4*)(orow));
        __builtin_nontemporal_store(o1, (f32x4*)(orow + 4));
    }
}

__global__ __launch_bounds__(256)
void k_fin(const unsigned short* __restrict__ P,
           const float* __restrict__ sample,
           const float* __restrict__ Z,
           float* __restrict__ out, int n0, int items) {
    combine_span(P, sample, Z, out, n0, items,
                 (int)(blockIdx.x * 256u + threadIdx.x),
                 (int)(gridDim.x * 256u));
}

// ---------------------------------------------------------------------------
// Fused mid: k_latm (blocks 0..319) + k_sample (blocks 320..359).
// latm: latb = bf16(tanh(outb · wlatb^T + b_latent)), XCD stripe, prefetch dbuf
// ---------------------------------------------------------------------------
__global__ __launch_bounds__(256)
void k_mid(const unsigned short* __restrict__ A,
           const unsigned short* __restrict__ B,
           const float* __restrict__ bias,
           unsigned short* __restrict__ dst,
           const float* __restrict__ a_arr,
           const float* __restrict__ dpar,
           float* __restrict__ sample) {
    if (blockIdx.x >= 320) {
        // k_sample body
        int i = ((int)blockIdx.x - 320) * 256 + (int)threadIdx.x;
        if (i >= MROWS) return;
        RKey root{0u, 42u};
        RKey ka = kfold(root, 0u);
        RKey kb = kfold(root, 1u);
        float lga = gamma_log(kfold(ka, (uint32_t)i), a_arr[i]);
        float lgb = gamma_log(kfold(kb, (uint32_t)i), dpar[i]);
        float lm = fmaxf(lga, lgb);
        float ea = expf(lga - lm), eb = expf(lgb - lm);
        sample[i] = ea / (ea + eb);
        return;
    }
    __shared__ unsigned short Als[2][128 * 64];   // 2 x 16 KB
    __shared__ unsigned short Bls[2][128 * 64];   // 2 x 16 KB
    const int tid  = threadIdx.x;
    const int lane = tid & 63, wid = tid >> 6;
    const int wm = wid >> 1, wn = wid & 1;
    const uint32_t l = blockIdx.x;             // 320 = 8 xcd * 40 cols
    const int row0 = (int)(l & 7u) * 128;      // row-stripe per XCD
    const int col0 = (int)(l >> 3) * 128;
    const int lrow8 = lane >> 3, lslot = lane & 7;

    const unsigned short* pA[4];
    const unsigned short* pB[4];
#pragma unroll
    for (int i = 0; i < 4; ++i) {
        int rA = wid * 32 + i * 8 + lrow8;
        pA[i] = A + (size_t)(row0 + rA) * NHID + ((lslot ^ (rA & 7)) << 3);
        int rB = wid * 32 + i * 8 + lrow8;
        pB[i] = B + (size_t)(col0 + rB) * NHID + ((lslot ^ (rB & 7)) << 3);
    }
    int offA[2][4], offB[2][4];
#pragma unroll
    for (int kh = 0; kh < 2; ++kh)
#pragma unroll
        for (int f = 0; f < 4; ++f) {
            int rA = wm * 64 + f * 16 + (lane & 15);
            offA[kh][f] = rA * 128 + ((((lane >> 4) * 16) + kh * 64) ^ ((rA & 7) << 4));
            int rB = wn * 64 + f * 16 + (lane & 15);
            offB[kh][f] = rB * 128 + ((((lane >> 4) * 16) + kh * 64) ^ ((rB & 7) << 4));
        }

    f32x4 acc[4][4];
#pragma unroll
    for (int mf = 0; mf < 4; ++mf)
#pragma unroll
        for (int nf = 0; nf < 4; ++nf) acc[mf][nf] = (f32x4)0.f;

#pragma unroll
    for (int i = 0; i < 4; ++i) {
        GLD16(pA[i], (char*)&Als[0][0] + (wid * 32 + i * 8) * 128); pA[i] += 64;
        GLD16(pB[i], (char*)&Bls[0][0] + (wid * 32 + i * 8) * 128); pB[i] += 64;
    }
    __syncthreads();

#pragma unroll
    for (int t = 0; t < 16; ++t) {
        const int cur = t & 1, nxt = cur ^ 1;
        if (t < 15) {
#pragma unroll
            for (int i = 0; i < 4; ++i) {
                GLD16(pA[i], (char*)&Als[nxt][0] + (wid * 32 + i * 8) * 128); pA[i] += 64;
                GLD16(pB[i], (char*)&Bls[nxt][0] + (wid * 32 + i * 8) * 128); pB[i] += 64;
            }
        }
        const char* Ab = (const char*)&Als[cur][0];
        const char* Bb = (const char*)&Bls[cur][0];
#pragma unroll
        for (int kh = 0; kh < 2; ++kh) {
            bf16x8 af[4], bfr[4];
#pragma unroll
            for (int f = 0; f < 4; ++f) {
                af[f]  = *(const bf16x8*)(Ab + offA[kh][f]);
                bfr[f] = *(const bf16x8*)(Bb + offB[kh][f]);
            }
#pragma unroll
            for (int mf = 0; mf < 4; ++mf)
#pragma unroll
                for (int nf = 0; nf < 4; ++nf)
                    acc[mf][nf] = __builtin_amdgcn_mfma_f32_16x16x32_bf16(
                        af[mf], bfr[nf], acc[mf][nf], 0, 0, 0);
        }
        __syncthreads();               // per-wave vmcnt(0): prefetch landed
    }

    const int q = lane >> 4, cl = lane & 15;
#pragma unroll
    for (int mf = 0; mf < 4; ++mf) {
#pragma unroll
        for (int nf = 0; nf < 4; ++nf) {
            int col = col0 + wn * 64 + nf * 16 + cl;
            float bc = bias[col];
#pragma unroll
            for (int j = 0; j < 4; ++j) {
                int r = row0 + wm * 64 + mf * 16 + q * 4 + j;
                dst[(size_t)r * NLAT + col] = f2b(tanhf(acc[mf][nf][j] + bc));
            }
        }
    }
}

// ---------------------------------------------------------------------------
// MFMA decoder pass: prefetch dbuf (verified round-15 structure) + XCD stripe
// + hoisted addressing. tile 160x128, BK=64, 4 waves, 5x4 frags 16x16x32.
// MODE 1: Z only  MODE 2: out=w*exp (fallback)
// MODE 3: Z + P-chunk via LDS-staged coalesced nt-stores (stride 272 B)
// MODE 3 fused: blocks >= nGemm run combine_span for the PREVIOUS chunk.
// ---------------------------------------------------------------------------
template<int MODE>
__global__ __launch_bounds__(256)
void k_dec(const unsigned short* __restrict__ A,
           const unsigned short* __restrict__ B,
           const float* __restrict__ bias,
           const float* __restrict__ wmix,
           float* __restrict__ dst,
           unsigned short* __restrict__ Pst,
           int rb0, int nRB, int nGemm,
           const float* __restrict__ sample,
           const float* __restrict__ Zarr,
           float* __restrict__ outp,
           const unsigned short* __restrict__ Pprev,
           int n0prev, int itemsPrev) {
    if (MODE == 3 && (int)blockIdx.x >= nGemm) {
        const int cb = (int)blockIdx.x - nGemm;
        combine_span(Pprev, sample, Zarr, outp, n0prev, itemsPrev,
                     cb * 256 + (int)threadIdx.x,
                     ((int)gridDim.x - nGemm) * 256);
        return;
    }
    // unified LDS arena: [0,40960) = Als[2], [40960,73728) = Bls[2];
    // epilogue reuses [0, 160*272) as P staging (row stride 272 B, 16B-aligned)
    __shared__ __align__(16) unsigned char lds_raw[73728];
    unsigned short (*Als)[160 * 64] = (unsigned short (*)[160 * 64])lds_raw;
    unsigned short (*Bls)[128 * 64] = (unsigned short (*)[128 * 64])(lds_raw + 40960);
    const int tid  = threadIdx.x;
    const int lane = tid & 63, wid = tid >> 6;
    const int wm = wid >> 1, wn = wid & 1;
    const uint32_t l = blockIdx.x;
    int by_l, bx;
    if (nRB >= 8 && (nRB & 7) == 0) {  // XCD stripe: xcd = l%8 owns nRB/8 rows
        const int per = nRB >> 3;
        const uint32_t jb = l >> 3;
        by_l = (int)(l & 7u) * per + (int)(jb % (uint32_t)per);
        bx   = (int)(jb / (uint32_t)per);
    } else {
        by_l = (int)(l % (uint32_t)nRB);
        bx   = (int)(l / (uint32_t)nRB);
    }
    const int by   = rb0 + by_l;
    const int row0 = by * 160;
    const int rl0  = by_l * 160;       // P-local row base
    const int col0 = bx * 128;
    const int lrow8 = lane >> 3, lslot = lane & 7;

    const unsigned short* pA[5];
    const unsigned short* pB[4];
#pragma unroll
    for (int i = 0; i < 5; ++i) {
        int rA = wid * 40 + i * 8 + lrow8;
        pA[i] = A + (size_t)(row0 + rA) * 512 + ((lslot ^ (rA & 7)) << 3);
    }
#pragma unroll
    for (int i = 0; i < 4; ++i) {
        int rB = wid * 32 + i * 8 + lrow8;
        pB[i] = B + (size_t)(col0 + rB) * 512 + ((lslot ^ (rB & 7)) << 3);
    }
    int offA[2][5], offB[2][4];
#pragma unroll
    for (int kh = 0; kh < 2; ++kh) {
#pragma unroll
        for (int mf = 0; mf < 5; ++mf) {
            int r = wm * 80 + mf * 16 + (lane & 15);
            offA[kh][mf] = r * 128 + ((((lane >> 4) * 16) + kh * 64) ^ ((r & 7) << 4));
        }
#pragma unroll
        for (int nf = 0; nf < 4; ++nf) {
            int r = wn * 64 + nf * 16 + (lane & 15);
            offB[kh][nf] = r * 128 + ((((lane >> 4) * 16) + kh * 64) ^ ((r & 7) << 4));
        }
    }

    f32x4 acc[5][4];
#pragma unroll
    for (int mf = 0; mf < 5; ++mf)
#pragma unroll
        for (int nf = 0; nf < 4; ++nf) acc[mf][nf] = (f32x4)0.f;

    // prologue: tile 0 -> buf 0
#pragma unroll
    for (int i = 0; i < 5; ++i) {
        GLD16(pA[i], (char*)&Als[0][0] + (wid * 40 + i * 8) * 128); pA[i] += 64;
    }
#pragma unroll
    for (int i = 0; i < 4; ++i) {
        GLD16(pB[i], (char*)&Bls[0][0] + (wid * 32 + i * 8) * 128); pB[i] += 64;
    }
    __syncthreads();

#pragma unroll
    for (int t = 0; t < 8; ++t) {
        const int cur = t & 1, nxt = cur ^ 1;
        if (t < 7) {
#pragma unroll
            for (int i = 0; i < 5; ++i) {
                GLD16(pA[i], (char*)&Als[nxt][0] + (wid * 40 + i * 8) * 128); pA[i] += 64;
            }
#pragma unroll
            for (int i = 0; i < 4; ++i) {
                GLD16(pB[i], (char*)&Bls[nxt][0] + (wid * 32 + i * 8) * 128); pB[i] += 64;
            }
        }
        const char* Ab = (const char*)&Als[cur][0];
        const char* Bb = (const char*)&Bls[cur][0];
#pragma unroll
        for (int kh = 0; kh < 2; ++kh) {
            bf16x8 af[5], bfr[4];
#pragma unroll
            for (int mf = 0; mf < 5; ++mf)
                af[mf] = *(const bf16x8*)(Ab + offA[kh][mf]);
#pragma unroll
            for (int nf = 0; nf < 4; ++nf)
                bfr[nf] = *(const bf16x8*)(Bb + offB[kh][nf]);
#pragma unroll
            for (int mf = 0; mf < 5; ++mf)
#pragma unroll
                for (int nf = 0; nf < 4; ++nf)
                    acc[mf][nf] = __builtin_amdgcn_mfma_f32_16x16x32_bf16(
                        af[mf], bfr[nf], acc[mf][nf], 0, 0, 0);
        }
        __syncthreads();               // per-wave vmcnt(0): prefetch landed
    }

    // C layout per frag: row = (lane>>4)*4 + j, col = lane&15  [m89-verified]
    const int q = lane >> 4, cl = lane & 15;
    float bv[4];
#pragma unroll
    for (int nf = 0; nf < 4; ++nf) bv[nf] = bias[col0 + wn * 64 + nf * 16 + cl];

    if (MODE == 3) {
        // exp + Z atomics + stage P tile into LDS (row stride 272 B)
#pragma unroll
        for (int mf = 0; mf < 5; ++mf) {
#pragma unroll
            for (int jj = 0; jj < 4; ++jj) {
                const int rr = wm * 80 + mf * 16 + q * 4 + jj;
                float p0 = expf(acc[mf][0][jj] + bv[0]);
                float p1 = expf(acc[mf][1][jj] + bv[1]);
                float p2 = expf(acc[mf][2][jj] + bv[2]);
                float p3 = expf(acc[mf][3][jj] + bv[3]);
                float s = ((p0 + p1) + (p2 + p3));
                s += __shfl_xor(s, 1); s += __shfl_xor(s, 2);
                s += __shfl_xor(s, 4); s += __shfl_xor(s, 8);
                if (cl == 0) atomicAdd(&dst[row0 + rr], s);
                unsigned short* lrow = (unsigned short*)(lds_raw + rr * 272);
                lrow[wn * 64 + cl]      = f2b(p0);
                lrow[wn * 64 + 16 + cl] = f2b(p1);
                lrow[wn * 64 + 32 + cl] = f2b(p2);
                lrow[wn * 64 + 48 + cl] = f2b(p3);
            }
        }
        __syncthreads();
        // coalesced writeout: 256 threads = 16 rows x 16 lanes, 10 passes
        const int rloc = tid >> 4, c16 = tid & 15;
#pragma unroll
        for (int it = 0; it < 10; ++it) {
            int gr = it * 16 + rloc;
            us16x8 v = *(const us16x8*)(lds_raw + gr * 272 + c16 * 16);
            __builtin_nontemporal_store(
                v, (us16x8*)(Pst + (size_t)(rl0 + gr) * NTOK + col0 + c16 * 8));
        }
    } else if (MODE == 1) {
#pragma unroll
        for (int mf = 0; mf < 5; ++mf) {
#pragma unroll
            for (int jj = 0; jj < 4; ++jj) {
                const int rr = wm * 80 + mf * 16 + q * 4 + jj;
                float p0 = expf(acc[mf][0][jj] + bv[0]);
                float p1 = expf(acc[mf][1][jj] + bv[1]);
                float p2 = expf(acc[mf][2][jj] + bv[2]);
                float p3 = expf(acc[mf][3][jj] + bv[3]);
                float s = ((p0 + p1) + (p2 + p3));
                s += __shfl_xor(s, 1); s += __shfl_xor(s, 2);
                s += __shfl_xor(s, 4); s += __shfl_xor(s, 8);
                if (cl == 0) atomicAdd(&dst[row0 + rr], s);
            }
        }
    } else {
        float wv[5][4];
#pragma unroll
        for (int mf = 0; mf < 5; ++mf)
#pragma unroll
            for (int jj = 0; jj < 4; ++jj)
                wv[mf][jj] = wmix[row0 + wm * 80 + mf * 16 + q * 4 + jj];
#pragma unroll
        for (int mf = 0; mf < 5; ++mf)
#pragma unroll
            for (int nf = 0; nf < 4; ++nf)
#pragma unroll
                for (int jj = 0; jj < 4; ++jj)
                    acc[mf][nf][jj] = wv[mf][jj] * expf(acc[mf][nf][jj] + bv[nf]);

        const int tok0 = by * 16 + wm * 8;
#pragma unroll
        for (int t = 0; t < 8; ++t) {
#pragma unroll
            for (int nf = 0; nf < 4; ++nf) {
                float s = 0.f;
#pragma unroll
                for (int i = 0; i < 10; ++i) {
                    const int rl = 10 * t + i;
                    const int mf = rl >> 4, qr = (rl >> 2) & 3, jj = rl & 3;
                    s += (q == qr) ? acc[mf][nf][jj] : 0.f;
                }
                s += __shfl_xor(s, 16);
                s += __shfl_xor(s, 32);
                if (q == 0)
                    dst[(size_t)(tok0 + t) * NTOK + col0 + wn * 64 + nf * 16 + cl] = s;
            }
        }
    }
}

// ---------------------------------------------------------------------------
extern "C" void kernel_launch(void* const* d_in, const int* in_sizes, int n_in,
                              void* d_out, int out_size, void* d_ws, size_t ws_size,
                              hipStream_t stream) {
    const float* output    = (const float*)d_in[0];  // [1024,1024]
    const float* W_latent  = (const float*)d_in[1];  // [5120,1024]
    const float* b_latent  = (const float*)d_in[2];  // [5120]
    const float* W_decoder = (const float*)d_in[3];  // [32000,512]
    const float* b_decoder = (const float*)d_in[4];  // [32000]
    const float* W_reduce  = (const float*)d_in[5];  // [10,1024]
    const float* b_reduce  = (const float*)d_in[6];  // [10]
    float* out = (float*)d_out;                      // [1024,32000]

    // ws layout: latb(10.49MB) | wdecb(32.77MB) | 6x f32[MROWS] | P buffers
    char* wsb = (char*)d_ws;
    unsigned short* latb  = (unsigned short*)wsb;
    unsigned short* wdecb = (unsigned short*)(wsb + 10485760);
    float* a_arr  = (float*)(wsb + 10485760 + 32768000);
    float* dpar   = a_arr  + MROWS;
    float* sample = dpar   + MROWS;
    float* pis    = sample + MROWS;
    float* Z      = pis    + MROWS;
    float* wmix   = Z      + MROWS;
    unsigned short* Pbuf = (unsigned short*)(wmix + MROWS);
    const size_t BASE = 10485760ull + 32768000ull + 6ull * MROWS * 4ull;
    const size_t avail = (ws_size > BASE) ? (ws_size - BASE) : 0;

    // choose: double-buffered chunk (fused combine) > single chunk > fallback
    int CRd = 0, CRs = 0;
    {
        const int cands[4] = {2560, 1280, 640, 320};
        for (int c = 0; c < 4; ++c)
            if (2ull * (size_t)cands[c] * NTOK * 2ull <= avail) { CRd = cands[c]; break; }
        if (CRd == 0) {
            const int cs[5] = {2560, 1280, 640, 320, 160};
            for (int c = 0; c < 5; ++c)
                if ((size_t)cs[c] * NTOK * 2ull <= avail) { CRs = cs[c]; break; }
        }
    }

    // bf16 copies of output/W_latent live in d_out (fully overwritten later)
    unsigned short* outb  = (unsigned short*)d_out;
    unsigned short* wlatb = (unsigned short*)((char*)d_out + 2097152);

    // fused prologue: 3 conversions + k_a + Z zeroing
    k_pre<<<11338, 256, 0, stream>>>(W_decoder, wdecb, output, outb,
                                     W_latent, wlatb, W_reduce, b_reduce,
                                     a_arr, dpar, Z);
    // fused mid: latent GEMM + beta sampling
    k_mid<<<360, 256, 0, stream>>>(outb, wlatb, b_latent, latb,
                                   a_arr, dpar, sample);

    if (CRd > 0) {
        // fused path: GEMM(ci) + combine(ci-1) in one launch, double Pbuf.
        const int nRB = CRd / 160, nGemm = nRB * 250, nch = MROWS / CRd;
        const int items = (CRd / 10) * 4000;
        for (int ci = 0; ci < nch; ++ci) {
            unsigned short* Pcur  = Pbuf + (size_t)(ci & 1) * CRd * NTOK;
            unsigned short* Pprev = Pbuf + (size_t)((ci & 1) ^ 1) * CRd * NTOK;
            const int extra = (ci > 0) ? 1000 : 0;
            k_dec<3><<<nGemm + extra, 256, 0, stream>>>(
                latb, wdecb, b_decoder, nullptr, Z, Pcur, ci * nRB, nRB, nGemm,
                sample, Z, out, Pprev, (ci - 1) * (CRd / 10), items);
        }
        unsigned short* Plast = Pbuf + (size_t)((nch - 1) & 1) * CRd * NTOK;
        k_fin<<<items / 256, 256, 0, stream>>>(Plast, sample, Z, out,
                                               (nch - 1) * (CRd / 10), items);
    } else if (CRs > 0) {
        // single-buffer chunked path
        const int nRB = CRs / 160;
        const int items = (CRs / 10) * 4000;
        for (int r0 = 0; r0 < MROWS; r0 += CRs) {
            k_dec<3><<<nRB * 250, 256, 0, stream>>>(
                latb, wdecb, b_decoder, nullptr, Z, Pbuf, r0 / 160, nRB, 1 << 30,
                sample, Z, out, nullptr, 0, 0);
            k_fin<<<items / 256, 256, 0, stream>>>(Pbuf, sample, Z, out,
                                                   r0 / 10, items);
        }
    } else {
        // fallback: two full GEMM passes
        k_pis<<<(NROW + 255) / 256, 256, 0, stream>>>(sample, pis);
        k_dec<1><<<16000, 256, 0, stream>>>(latb, wdecb, b_decoder, nullptr, Z,
                                            nullptr, 0, 64, 1 << 30,
                                            sample, Z, out, nullptr, 0, 0);
        k_w<<<MROWS / 256, 256, 0, stream>>>(pis, Z, wmix, 0, MROWS);
        k_dec<2><<<16000, 256, 0, stream>>>(latb, wdecb, b_decoder, wmix, out,
                                            nullptr, 0, 64, 1 << 30,
                                            sample, Z, out, nullptr, 0, 0);
    }
    (void)in_sizes; (void)n_in; (void)out_size;
}